// Round 9
// baseline (283.795 us; speedup 1.0000x reference)
//
#include <hip/hip_runtime.h>

// ---------------------------------------------------------------------------
// FullMHLA: B=2, T=1024, C=2048, NH=16, NLQ=512, NLKV=512, DHR=64, HS=128.
// Round 18: merge1 j0 (QKV GEMM, was 160 blocks = 0.625/CU, 32 K-steps) is
// now split-K x4 (640 blocks of K=512) -> fp32 partials in the Opart region
// (time-disjoint reuse), reduced by vred2 together with the old Vprt reduce.
// merge1 = 896 blocks (3.5/CU). Everything else byte-identical to R17
// (dbuf GEMM for merge1/merge2, single-buffered merge3, R0 attn_part).
// ---------------------------------------------------------------------------
#define Bv   2
#define Tv   1024
#define Cv   2048
#define NHv  16

typedef unsigned short u16;
typedef __attribute__((ext_vector_type(8))) short bf8_t;
typedef __attribute__((ext_vector_type(4))) float f4_t;
typedef __attribute__((ext_vector_type(4))) unsigned short u16x4;
typedef __attribute__((ext_vector_type(8))) unsigned short u16x8;

__device__ __forceinline__ u16 f2bf(float f) {
  union { float f; unsigned u; } v; v.f = f;
  unsigned r = v.u + 0x7fffu + ((v.u >> 16) & 1u);   // RNE
  return (u16)(r >> 16);
}
__device__ __forceinline__ float bf2f(u16 b) {
  return __uint_as_float((unsigned)b << 16);
}
__device__ __forceinline__ void glds16(const u16* gp, u16* lp) {
  __builtin_amdgcn_global_load_lds(
      (const __attribute__((address_space(1))) void*)gp,
      (__attribute__((address_space(3))) void*)lp, 16, 0, 0);
}

// ---------------------------------------------------------------------------
// Multi-job bf16 NT MFMA GEMM: C = A * B^T. 128x128 tile, BK=64, 256 thr.
// ---------------------------------------------------------------------------
struct Job {
  const u16* A; const u16* B; void* C;
  long sA1, sA2, sB1, sB2, sC1, sC2;
  int K, lda, ldb, ldc, Nact, zdiv, ntx, nty, out_bf;
};
struct JobPack3 { Job j[3]; int cum[4]; };

// ---- single-buffered variant (used for K=128 job where occupancy matters)
__global__ __launch_bounds__(256) void gemm_multi(JobPack3 P) {
  const int bid = blockIdx.x;
  const int ji = (bid >= P.cum[1] ? 1 : 0) + (bid >= P.cum[2] ? 1 : 0);
  const Job& J = P.j[ji];
  int local = bid - P.cum[ji];
  const int x = local % J.ntx;
  int rest = local / J.ntx;
  const int y = rest % J.nty;
  const int z = rest / J.nty;
  const int m0 = y * 128, n0 = x * 128;

  const int z1 = z / J.zdiv, z2 = z % J.zdiv;
  const u16* A = J.A + z1 * J.sA1 + z2 * J.sA2;
  const u16* B = J.B + z1 * J.sB1 + z2 * J.sB2;
  const int K = J.K, lda = J.lda, ldb = J.ldb, ldc = J.ldc, Nact = J.Nact;

  __shared__ u16 SMEM[16384];
  u16* As = SMEM;
  u16* Bs = SMEM + 8192;

  const int tid = threadIdx.x, w = tid >> 6, ln = tid & 63;
  const int my = w >> 1, mx = w & 1;
  const int g = ln >> 4, m = ln & 15;

  f4_t acc[4][4];
#pragma unroll
  for (int i = 0; i < 4; ++i)
#pragma unroll
    for (int j = 0; j < 4; ++j) acc[i][j] = (f4_t)0.f;

  for (int k0 = 0; k0 < K; k0 += 64) {
#pragma unroll
    for (int q = 0; q < 4; ++q) {
      int r = 32 * w + 8 * q + (ln >> 3);
      int c = ((ln & 7) - r) & 7;
      glds16(&A[(long)(m0 + r) * lda + k0 + c * 8], &As[(32 * w + 8 * q) * 64]);
      glds16(&B[(long)(n0 + r) * ldb + k0 + c * 8], &Bs[(32 * w + 8 * q) * 64]);
    }
    __syncthreads();
#pragma unroll
    for (int kh = 0; kh < 2; ++kh) {
      bf8_t af[4], bg[4];
#pragma unroll
      for (int mt = 0; mt < 4; ++mt) {
        int row = my * 64 + mt * 16 + m;
        af[mt] = *(const bf8_t*)&As[row * 64 + (((kh * 4 + g) + row) & 7) * 8];
      }
#pragma unroll
      for (int nt = 0; nt < 4; ++nt) {
        int row = mx * 64 + nt * 16 + m;
        bg[nt] = *(const bf8_t*)&Bs[row * 64 + (((kh * 4 + g) + row) & 7) * 8];
      }
#pragma unroll
      for (int mt = 0; mt < 4; ++mt)
#pragma unroll
        for (int nt = 0; nt < 4; ++nt)
          acc[mt][nt] = __builtin_amdgcn_mfma_f32_16x16x32_bf16(
              af[mt], bg[nt], acc[mt][nt], 0, 0, 0);
    }
    __syncthreads();
  }

  if (J.out_bf) {
    u16* Es = SMEM + w * 4096;
#pragma unroll
    for (int mt = 0; mt < 4; ++mt)
#pragma unroll
      for (int nt = 0; nt < 4; ++nt)
#pragma unroll
        for (int r = 0; r < 4; ++r) {
          int row = mt * 16 + g * 4 + r;
          int col = nt * 16 + m;
          Es[row * 64 + (((col >> 3) + row) & 7) * 8 + (col & 7)] =
              f2bf(acc[mt][nt][r]);
        }
    __syncthreads();
    u16* C = (u16*)J.C + z1 * J.sC1 + z2 * J.sC2;
    const long rowbase = (long)(m0 + my * 64 + ln) * ldc + n0 + mx * 64;
#pragma unroll
    for (int c = 0; c < 8; ++c) {
      if (n0 + mx * 64 + c * 8 < Nact) {
        u16x8 v = *(const u16x8*)&Es[ln * 64 + ((c + ln) & 7) * 8];
        *(u16x8*)&C[rowbase + c * 8] = v;
      }
    }
  } else {
    float* C = (float*)J.C + z1 * J.sC1 + z2 * J.sC2;
#pragma unroll
    for (int mt = 0; mt < 4; ++mt)
#pragma unroll
      for (int nt = 0; nt < 4; ++nt)
#pragma unroll
        for (int r = 0; r < 4; ++r) {
          int row = m0 + my * 64 + mt * 16 + g * 4 + r;
          int col = n0 + mx * 64 + nt * 16 + m;
          if (col < Nact) C[(long)row * ldc + col] = acc[mt][nt][r];
        }
  }
}

// ---- double-buffered variant: stage t+1 before compute t, 1 barrier/K-step.
__global__ __launch_bounds__(256) void gemm_db(JobPack3 P) {
  const int bid = blockIdx.x;
  const int ji = (bid >= P.cum[1] ? 1 : 0) + (bid >= P.cum[2] ? 1 : 0);
  const Job& J = P.j[ji];
  int local = bid - P.cum[ji];
  const int x = local % J.ntx;
  int rest = local / J.ntx;
  const int y = rest % J.nty;
  const int z = rest / J.nty;
  const int m0 = y * 128, n0 = x * 128;

  const int z1 = z / J.zdiv, z2 = z % J.zdiv;
  const u16* A = J.A + z1 * J.sA1 + z2 * J.sA2;
  const u16* B = J.B + z1 * J.sB1 + z2 * J.sB2;
  const int K = J.K, lda = J.lda, ldb = J.ldb, ldc = J.ldc, Nact = J.Nact;

  __shared__ u16 SMEM[32768];   // 2 x (As 16KB + Bs 16KB)

  const int tid = threadIdx.x, w = tid >> 6, ln = tid & 63;
  const int my = w >> 1, mx = w & 1;
  const int g = ln >> 4, m = ln & 15;

  // per-thread staging coords (loop-invariant)
  const int sr = (ln >> 3);            // +8q +32w below
  const int nk = K >> 6;

  f4_t acc[4][4];
#pragma unroll
  for (int i = 0; i < 4; ++i)
#pragma unroll
    for (int j = 0; j < 4; ++j) acc[i][j] = (f4_t)0.f;

  // prologue: stage tile 0 into buf 0
  {
    u16* As = SMEM;
    u16* Bs = SMEM + 8192;
#pragma unroll
    for (int q = 0; q < 4; ++q) {
      int r = 32 * w + 8 * q + sr;
      int c = ((ln & 7) - r) & 7;
      glds16(&A[(long)(m0 + r) * lda + c * 8], &As[(32 * w + 8 * q) * 64]);
      glds16(&B[(long)(n0 + r) * ldb + c * 8], &Bs[(32 * w + 8 * q) * 64]);
    }
  }
  __syncthreads();

  int buf = 0;
#pragma unroll 1
  for (int t = 0; t < nk; ++t) {
    // stage t+1 into the other buffer FIRST (latency hides under MFMA below)
    if (t + 1 < nk) {
      const int k0 = (t + 1) * 64;
      u16* As = SMEM + (buf ^ 1) * 16384;
      u16* Bs = As + 8192;
#pragma unroll
      for (int q = 0; q < 4; ++q) {
        int r = 32 * w + 8 * q + sr;
        int c = ((ln & 7) - r) & 7;
        glds16(&A[(long)(m0 + r) * lda + k0 + c * 8],
               &As[(32 * w + 8 * q) * 64]);
        glds16(&B[(long)(n0 + r) * ldb + k0 + c * 8],
               &Bs[(32 * w + 8 * q) * 64]);
      }
    }
    // compute tile t from buf (data guaranteed by previous barrier)
    {
      const u16* As = SMEM + buf * 16384;
      const u16* Bs = As + 8192;
#pragma unroll
      for (int kh = 0; kh < 2; ++kh) {
        bf8_t af[4], bg[4];
#pragma unroll
        for (int mt = 0; mt < 4; ++mt) {
          int row = my * 64 + mt * 16 + m;
          af[mt] = *(const bf8_t*)&As[row * 64 + (((kh * 4 + g) + row) & 7) * 8];
        }
#pragma unroll
        for (int nt = 0; nt < 4; ++nt) {
          int row = mx * 64 + nt * 16 + m;
          bg[nt] = *(const bf8_t*)&Bs[row * 64 + (((kh * 4 + g) + row) & 7) * 8];
        }
#pragma unroll
        for (int mt = 0; mt < 4; ++mt)
#pragma unroll
          for (int nt = 0; nt < 4; ++nt)
            acc[mt][nt] = __builtin_amdgcn_mfma_f32_16x16x32_bf16(
                af[mt], bg[nt], acc[mt][nt], 0, 0, 0);
      }
    }
    __syncthreads();   // drains stage(t+1) loads; joins readers of buf
    buf ^= 1;
  }

  if (J.out_bf) {
    u16* Es = SMEM + w * 4096;
#pragma unroll
    for (int mt = 0; mt < 4; ++mt)
#pragma unroll
      for (int nt = 0; nt < 4; ++nt)
#pragma unroll
        for (int r = 0; r < 4; ++r) {
          int row = mt * 16 + g * 4 + r;
          int col = nt * 16 + m;
          Es[row * 64 + (((col >> 3) + row) & 7) * 8 + (col & 7)] =
              f2bf(acc[mt][nt][r]);
        }
    __syncthreads();
    u16* C = (u16*)J.C + z1 * J.sC1 + z2 * J.sC2;
    const long rowbase = (long)(m0 + my * 64 + ln) * ldc + n0 + mx * 64;
#pragma unroll
    for (int c = 0; c < 8; ++c) {
      if (n0 + mx * 64 + c * 8 < Nact) {
        u16x8 v = *(const u16x8*)&Es[ln * 64 + ((c + ln) & 7) * 8];
        *(u16x8*)&C[rowbase + c * 8] = v;
      }
    }
  } else {
    float* C = (float*)J.C + z1 * J.sC1 + z2 * J.sC2;
#pragma unroll
    for (int mt = 0; mt < 4; ++mt)
#pragma unroll
      for (int nt = 0; nt < 4; ++nt)
#pragma unroll
        for (int r = 0; r < 4; ++r) {
          int row = m0 + my * 64 + mt * 16 + g * 4 + r;
          int col = n0 + mx * 64 + nt * 16 + m;
          if (col < Nact) C[(long)row * ldc + col] = acc[mt][nt][r];
        }
  }
}

// ---------------------------------------------------------------------------
// Split-flash attention, pass 1. (Byte-exact R0 baseline.)
// ---------------------------------------------------------------------------
__global__ __launch_bounds__(256, 3) void attn_part(
    const u16* __restrict__ Qcat,   // (B,NH,T,576)
    const u16* __restrict__ Kcat,   // (B,T,576) roped
    const u16* __restrict__ ZT,     // (B,NH,128,1024)
    float* __restrict__ Opart,      // (1280,64,128)
    float* __restrict__ ml,         // (1280,2,64)
    float* __restrict__ out) {      // (B,T,2048)
  const int x = blockIdx.x;          // 1280
  const int bh = x & 31, item = x >> 5;  // 0..39
  const int b = bh >> 4, h = bh & 15;
  // heavy (2-s-tile) items first, 8 light items last
  static const int qtab[40] = {2,3,4,5,6,6,7,7,8,8,9,9,10,10,10,11,11,11,
                               12,12,12,13,13,13,14,14,14,14,15,15,15,15,
                               0,1,4,5,8,9,12,13};
  static const int ctab[40] = {0,0,0,0,0,1,0,1,0,1,0,1,0,1,2,0,1,2,
                               0,1,2,0,1,2,0,1,2,3,0,1,2,3,
                               0,0,1,1,2,2,3,3};
  const int qt = qtab[item], ch = ctab[item];
  const int ns = (qt >> 1) + 1;             // causal s-tiles for this q-tile
  const int s0t = 2 * ch, s1t = min(2 * ch + 2, ns);
  const bool full = (ch == 0) && (qt <= 3);

  __shared__ u16 As[4096];    // Q-tile 64x64
  __shared__ u16 Bs[8192];    // K/ZT-tile 128x64
  __shared__ u16 Ps[8192];    // P 64x128, chunk-swizzle mod 16

  const int tid = threadIdx.x, w = tid >> 6, ln = tid & 63;
  const int g = ln >> 4, m = ln & 15;

  const u16* Qb = Qcat + (long)bh * 589824 + (long)qt * 64 * 576;
  const u16* Kb = Kcat + (long)b * 589824;
  const u16* Zb = ZT + (long)bh * 131072;

  f4_t O[8];
#pragma unroll
  for (int j = 0; j < 8; ++j) O[j] = (f4_t)0.f;
  float mrow[4], lrow[4];
#pragma unroll
  for (int r = 0; r < 4; ++r) { mrow[r] = -3e38f; lrow[r] = 0.f; }

  const float scale = 0.07216878364870322f;  // 1/sqrt(192)

  for (int st = s0t; st < s1t; ++st) {
    f4_t S[8];
#pragma unroll
    for (int j = 0; j < 8; ++j) S[j] = (f4_t)0.f;

    // ---- QK: 9 BK-iters over K=576
    for (int k0 = 0; k0 < 576; k0 += 64) {
#pragma unroll
      for (int q = 0; q < 2; ++q) {
        int r = 16 * w + 8 * q + (ln >> 3);
        int c = ((ln & 7) - r) & 7;
        glds16(&Qb[(long)r * 576 + k0 + c * 8], &As[(16 * w + 8 * q) * 64]);
      }
#pragma unroll
      for (int q = 0; q < 4; ++q) {
        int r = 32 * w + 8 * q + (ln >> 3);
        int c = ((ln & 7) - r) & 7;
        glds16(&Kb[(long)(st * 128 + r) * 576 + k0 + c * 8],
               &Bs[(32 * w + 8 * q) * 64]);
      }
      __syncthreads();
#pragma unroll
      for (int kh = 0; kh < 2; ++kh) {
        int qrow = 16 * w + m;
        bf8_t af = *(const bf8_t*)&As[qrow * 64 + (((kh * 4 + g) + qrow) & 7) * 8];
#pragma unroll
        for (int nt = 0; nt < 8; ++nt) {
          int row = nt * 16 + m;
          bf8_t bb = *(const bf8_t*)&Bs[row * 64 + (((kh * 4 + g) + row) & 7) * 8];
          S[nt] = __builtin_amdgcn_mfma_f32_16x16x32_bf16(af, bb, S[nt], 0, 0, 0);
        }
      }
      __syncthreads();
    }

    // ---- scale + causal mask (diag s-tile only)
    const bool diag = (st == (qt >> 1));
#pragma unroll
    for (int nt = 0; nt < 8; ++nt)
#pragma unroll
      for (int r = 0; r < 4; ++r) {
        float v = S[nt][r] * scale;
        if (diag &&
            (st * 128 + nt * 16 + m) > (qt * 64 + 16 * w + g * 4 + r))
          v = -3e38f;
        S[nt][r] = v;
      }

    // ---- online softmax (rows wave-local; 16-lane butterflies over m)
#pragma unroll
    for (int r = 0; r < 4; ++r) {
      float mx = S[0][r];
#pragma unroll
      for (int nt = 1; nt < 8; ++nt) mx = fmaxf(mx, S[nt][r]);
#pragma unroll
      for (int o = 1; o < 16; o <<= 1) mx = fmaxf(mx, __shfl_xor(mx, o, 64));
      float mn = fmaxf(mrow[r], mx);
      float al = __expf(mrow[r] - mn);
      mrow[r] = mn;
      float rs = 0.f;
#pragma unroll
      for (int nt = 0; nt < 8; ++nt) {
        float p = __expf(S[nt][r] - mn);
        S[nt][r] = p;
        rs += p;
      }
#pragma unroll
      for (int o = 1; o < 16; o <<= 1) rs += __shfl_xor(rs, o, 64);
      lrow[r] = lrow[r] * al + rs;
#pragma unroll
      for (int nt = 0; nt < 8; ++nt) O[nt][r] *= al;
    }

    // ---- P~ -> LDS (wave-local 16 rows; mod-16 chunk swizzle)
#pragma unroll
    for (int nt = 0; nt < 8; ++nt) {
      int colc = nt * 2 + (m >> 3), cole = m & 7;
#pragma unroll
      for (int r = 0; r < 4; ++r) {
        int row = 16 * w + g * 4 + r;
        Ps[row * 128 + ((colc + row) & 15) * 8 + cole] = f2bf(S[nt][r]);
      }
    }

    // ---- PV: O += P~ . ZT-sliceT (K=128, 2 BK-iters)
#pragma unroll
    for (int kb = 0; kb < 2; ++kb) {
      __syncthreads();  // Bs reuse guard
#pragma unroll
      for (int q = 0; q < 4; ++q) {
        int r = 32 * w + 8 * q + (ln >> 3);
        int c = ((ln & 7) - r) & 7;
        glds16(&Zb[(long)r * 1024 + st * 128 + kb * 64 + c * 8],
               &Bs[(32 * w + 8 * q) * 64]);
      }
      __syncthreads();
#pragma unroll
      for (int kh = 0; kh < 2; ++kh) {
        int qrow = 16 * w + m;
        int chk = kb * 8 + kh * 4 + g;
        bf8_t af = *(const bf8_t*)&Ps[qrow * 128 + ((chk + qrow) & 15) * 8];
#pragma unroll
        for (int nt = 0; nt < 8; ++nt) {
          int row = nt * 16 + m;
          bf8_t bb = *(const bf8_t*)&Bs[row * 64 + (((kh * 4 + g) + row) & 7) * 8];
          O[nt] = __builtin_amdgcn_mfma_f32_16x16x32_bf16(af, bb, O[nt], 0, 0, 0);
        }
      }
    }
    __syncthreads();  // protect As/Bs/Ps for next s-tile
  }

  if (full) {
    // ---- direct write: y = O/l (block saw the whole causal range)
    float* ob = out + ((long)b * Tv + qt * 64 + 16 * w) * 2048 + h * 128;
#pragma unroll
    for (int r = 0; r < 4; ++r) {
      float inv = 1.0f / lrow[r];
#pragma unroll
      for (int nt = 0; nt < 8; ++nt)
        ob[(long)(g * 4 + r) * 2048 + nt * 16 + m] = O[nt][r] * inv;
    }
  } else {
    // ---- emit partials: Opart (unnormalized), ml (m, l per row)
    float* Ob = Opart + (long)x * 8192;
#pragma unroll
    for (int r = 0; r < 4; ++r) {
      int row = 16 * w + g * 4 + r;
#pragma unroll
      for (int nt = 0; nt < 8; ++nt)
        Ob[(long)row * 128 + nt * 16 + m] = O[nt][r];
      if (m == 0) {
        ml[(long)x * 128 + row] = mrow[r];
        ml[(long)x * 128 + 64 + row] = lrow[r];
      }
    }
  }
}

// ---------------------------------------------------------------------------
// Split-flash pass 2: merge partials for qt>=4, write y fp32.
// Grid 1536 = (12 qt x 32 bh) x 4 row-groups; 256 thr = 8 rows x 32 float4.
// ---------------------------------------------------------------------------
__global__ __launch_bounds__(256) void attn_merge(
    const float* __restrict__ Opart, const float* __restrict__ ml,
    float* __restrict__ out) {
  const int i = blockIdx.x;
  const int rg = i & 3;                // 16-row group
  const int combo = i >> 2;            // 0..383
  const int bh = combo & 31, qt = 4 + (combo >> 5);  // 4..15
  const int b = bh >> 4, h = bh & 15;
  static const int NCH[16] = {1,1,1,1,2,2,2,2,3,3,3,3,4,4,4,4};
  static const int ITEM[64] = {
      32,0,0,0,  33,0,0,0,  0,0,0,0,   1,0,0,0,
      2,34,0,0,  3,35,0,0,  4,5,0,0,   6,7,0,0,
      8,9,36,0,  10,11,37,0, 12,13,14,0, 15,16,17,0,
      18,19,20,38, 21,22,23,39, 24,25,26,27, 28,29,30,31};
  const int nch = NCH[qt];
  const int r = threadIdx.x >> 5, c4 = threadIdx.x & 31;
  float* ob = out + ((long)b * Tv + qt * 64 + rg * 16) * 2048 + h * 128;
#pragma unroll
  for (int rr = 0; rr < 2; ++rr) {
    const int lrow = r + rr * 8;          // 0..15 within group
    const int row = rg * 16 + lrow;       // 0..63 absolute
    float M = -3e38f, mi[4], li[4];
    for (int k = 0; k < nch; ++k) {
      long p = (long)ITEM[qt * 4 + k] * 32 + bh;
      mi[k] = ml[p * 128 + row];
      li[k] = ml[p * 128 + 64 + row];
      M = fmaxf(M, mi[k]);
    }
    float L = 0.f;
    float ax = 0.f, ay = 0.f, az = 0.f, aw = 0.f;
    for (int k = 0; k < nch; ++k) {
      long p = (long)ITEM[qt * 4 + k] * 32 + bh;
      float e = __expf(mi[k] - M);
      L += li[k] * e;
      float4 v = *(const float4*)&Opart[p * 8192 + (long)row * 128 + c4 * 4];
      ax += v.x * e; ay += v.y * e; az += v.z * e; aw += v.w * e;
    }
    const float inv = 1.0f / L;
    float4 o4 = {ax * inv, ay * inv, az * inv, aw * inv};
    *(float4*)&ob[(long)lrow * 2048 + c4 * 4] = o4;
  }
}

// ---------------------------------------------------------------------------
// Fused fp32->bf16 casts (5 segments) + Wkr pad into W3
// ---------------------------------------------------------------------------
struct CastArgs {
  const float* src[6];
  u16* dst[6];
  long cum[7];
  const float* wkr;
  u16* w3;
};
__global__ void cast_all(CastArgs a, long total4) {
  long i = (long)blockIdx.x * 256 + threadIdx.x;
  if (i < total4) {
    int seg = 0;
    while (i >= a.cum[seg + 1]) ++seg;
    long j = i - a.cum[seg];
    float4 vv = ((const float4*)a.src[seg])[j];
    u16x4 o;
    o[0] = f2bf(vv.x); o[1] = f2bf(vv.y); o[2] = f2bf(vv.z); o[3] = f2bf(vv.w);
    ((u16x4*)a.dst[seg])[j] = o;
  } else {
    long j = i - total4;  // < 98304
    u16x4* W4 = (u16x4*)a.w3;
    if (j < 32768) {
      float4 vv = ((const float4*)a.wkr)[j];
      u16x4 o;
      o[0] = f2bf(vv.x); o[1] = f2bf(vv.y); o[2] = f2bf(vv.z); o[3] = f2bf(vv.w);
      W4[557056 + j] = o;                    // rows 1088..1151
    } else if (j < 65536) {
      W4[262144 + (j - 32768)] = (u16x4)0;   // rows 512..575
    } else {
      W4[589824 + (j - 65536)] = (u16x4)0;   // rows 1152..1215
    }
  }
}

// ---------------------------------------------------------------------------
// fp32 (R x C) -> bf16 transpose (C x R); 3 jobs via flat block id.
// job0: Wuk (2048x512)->WukT, job1: Wuv (2048x512)->WuvT,
// job2: Wuq buffer viewed (512x2048) -> WuqT (2048x512) = U^T.
// ---------------------------------------------------------------------------
struct TcArgs { const float* s[3]; u16* d[3]; };
__global__ __launch_bounds__(256) void tcastg(TcArgs a) {
  const int bid = blockIdx.x;          // 3072
  const int job = bid >> 10, t = bid & 1023;
  const float* in = a.s[job];
  u16* out = a.d[job];
  const int R = (job == 2) ? 512 : 2048;
  const int C = (job == 2) ? 2048 : 512;
  const int xt = (job == 2) ? 64 : 16;   // C/32 tiles along columns
  const int x = t % xt, y = t / xt;
  __shared__ u16 sm[32][33];
  const int c0 = x * 32, r0 = y * 32;
  const int tx = threadIdx.x & 31, ty = threadIdx.x >> 5;
  for (int i = ty; i < 32; i += 8)
    sm[i][tx] = f2bf(in[(long)(r0 + i) * C + c0 + tx]);
  __syncthreads();
  for (int i = ty; i < 32; i += 8)
    out[(long)(c0 + i) * R + r0 + tx] = sm[tx][i];
}

// Fused ropes: idx<65536 -> Kcat cols 512..575 in place;
// else rope+scatter cqr (B,T,NH*64) -> Qcat (B,NH,T,576) cols 512..575.
__global__ void rope_fused(u16* __restrict__ Kcat, const u16* __restrict__ cqr,
                           u16* __restrict__ Qcat,
                           const float* __restrict__ cosf,
                           const float* __restrict__ sinf) {
  int idx = blockIdx.x * 256 + threadIdx.x;  // < 1,114,112
  if (idx < 65536) {
    int i = idx & 31, t = (idx >> 5) & 1023, b = idx >> 15;
    float c = cosf[t * 32 + i], s = sinf[t * 32 + i];
    u16* p = Kcat + ((long)(b * Tv + t) * 576 + 512 + 2 * i);
    float re = bf2f(p[0]), im = bf2f(p[1]);
    p[0] = f2bf(re * c - im * s);
    p[1] = f2bf(re * s + im * c);
  } else {
    int j = idx - 65536;  // < 1,048,576
    int i = j & 31, h = (j >> 5) & 15, t = (j >> 9) & 1023, b = j >> 19;
    float c = cosf[t * 32 + i], s = sinf[t * 32 + i];
    const u16* src = cqr + ((long)(b * Tv + t) * 1024 + h * 64 + 2 * i);
    float re = bf2f(src[0]), im = bf2f(src[1]);
    u16* dst = Qcat + (((long)(b * NHv + h) * Tv + t) * 576 + 512 + 2 * i);
    dst[0] = f2bf(re * c - im * s);
    dst[1] = f2bf(re * s + im * c);
  }
}

// ---------------------------------------------------------------------------
// vred2: fused reduce of (a) 4 fp32 split-K partials (2048x512) -> bf16 veffT
// and (b) 4 fp32 QKV split-K partials (2048x1152) -> bf16 cq / Kcat.
// Grid 3328 x 256: i < 262144 -> veffT; else j < 589824 -> cq/Kcat.
// ---------------------------------------------------------------------------
__global__ void vred2(const float* __restrict__ Vp, u16* __restrict__ veffT,
                      const float* __restrict__ Qp, u16* __restrict__ cq,
                      u16* __restrict__ Kcat) {
  long i = (long)blockIdx.x * 256 + threadIdx.x;
  if (i < 262144) {
    float4 v0 = ((const float4*)Vp)[i];
    float4 v1 = ((const float4*)Vp)[262144 + i];
    float4 v2 = ((const float4*)Vp)[524288 + i];
    float4 v3 = ((const float4*)Vp)[786432 + i];
    u16x4 o;
    o[0] = f2bf(v0.x + v1.x + v2.x + v3.x);
    o[1] = f2bf(v0.y + v1.y + v2.y + v3.y);
    o[2] = f2bf(v0.z + v1.z + v2.z + v3.z);
    o[3] = f2bf(v0.w + v1.w + v2.w + v3.w);
    ((u16x4*)veffT)[i] = o;
  } else {
    long j = i - 262144;            // < 589824 = 2048*1152/4
    int col4 = (int)(j % 288), row = (int)(j / 288);
    long base = (long)row * 288 + col4;
    const float4* P0 = (const float4*)Qp;
    float4 v0 = P0[base];
    float4 v1 = P0[589824 + base];
    float4 v2 = P0[1179648 + base];
    float4 v3 = P0[1769472 + base];
    u16x4 o;
    o[0] = f2bf(v0.x + v1.x + v2.x + v3.x);
    o[1] = f2bf(v0.y + v1.y + v2.y + v3.y);
    o[2] = f2bf(v0.z + v1.z + v2.z + v3.z);
    o[3] = f2bf(v0.w + v1.w + v2.w + v3.w);
    int c = col4 * 4;
    u16* dst = (c < 576) ? (cq + (long)row * 576 + c)
                         : (Kcat + (long)row * 576 + (c - 576));
    *(u16x4*)dst = o;
  }
}

// ---------------------------------------------------------------------------
// kernel_launch
// ---------------------------------------------------------------------------
extern "C" void kernel_launch(void* const* d_in, const int* in_sizes, int n_in,
                              void* d_out, int out_size, void* d_ws,
                              size_t ws_size, hipStream_t stream) {
  const float* x    = (const float*)d_in[0];
  const float* fcos = (const float*)d_in[1];
  const float* fsin = (const float*)d_in[2];
  const float* Wdq  = (const float*)d_in[3];
  const float* Wuq  = (const float*)d_in[4];
  const float* Wdkv = (const float*)d_in[5];
  const float* Wuk  = (const float*)d_in[6];
  const float* Wuv  = (const float*)d_in[7];
  const float* Wqr  = (const float*)d_in[8];
  const float* Wkr  = (const float*)d_in[9];
  const float* Wo   = (const float*)d_in[10];
  float* out = (float*)d_out;

  // ---- workspace carve-up (u16 units; total ~154 MB < 256 MiB)
  u16* ws = (u16*)d_ws;
  u16* cq     = ws;                  // (2048x576)        1,179,648
  u16* Kcat   = cq + 1179648;        // (B,T,576)         1,179,648
  u16* veffT  = Kcat + 1179648;      // (2048x512)        1,048,576
  u16* Qcat   = veffT + 1048576;     // (B,NH,T,576)     18,874,368
  u16* W3     = Qcat + 18874368;     // (1216x2048)       2,490,368
  u16* x_bf   = W3 + 2490368;        //                   4,194,304
  u16* Wqr_bf = x_bf + 4194304;      //                     524,288
  u16* WuqT   = Wqr_bf + 524288;     // (2048x512) = U^T  1,048,576
  u16* Wo_bf  = WuqT + 1048576;      //                   4,194,304
  u16* WukT   = Wo_bf + 4194304;     // (512x2048)        1,048,576
  u16* WuvT   = WukT + 1048576;      // (512x2048)        1,048,576
  u16* cqr    = WuvT + 1048576;      // (B,T,1024)        2,097,152
  u16* qup    = cqr + 2097152;       // (2048x2048)       4,194,304
  u16* ZTbuf  = qup + 4194304;       // (B,NH,128,1024)   4,194,304
  float* Vprt  = (float*)(ZTbuf + 4194304);   // 4x(2048x512) fp32
  float* Opart = Vprt + 4194304;              // 1280x64x128 fp32
  float* mlbuf = Opart + 10485760;            // 1280x2x64 fp32
  // QKV split-K fp32 partials: 4 x (2048x1152) = 9,437,184 floats.
  // Time-disjoint reuse of the Opart region (Opart written only by attn_part,
  // long after vred2 consumed these partials). 9.4M < Opart's 10.49M floats.
  float* Qprt  = Opart;

  // ---- 1) casts (+Wkr pad); Wuq no longer needs a flat bf16 copy
  {
    CastArgs a;
    a.src[0] = x;    a.dst[0] = x_bf;
    a.src[1] = Wdq;  a.dst[1] = W3;
    a.src[2] = Wdkv; a.dst[2] = W3 + 576 * 2048;
    a.src[3] = Wqr;  a.dst[3] = Wqr_bf;
    a.src[4] = Wo;   a.dst[4] = Wo_bf;
    a.src[5] = Wo;   a.dst[5] = Wo_bf;   // unused
    a.cum[0] = 0;        a.cum[1] = 1048576; a.cum[2] = 1310720;
    a.cum[3] = 1572864;  a.cum[4] = 1703936; a.cum[5] = 2752512;
    a.cum[6] = 2752512;
    a.wkr = Wkr; a.w3 = W3;
    cast_all<<<11136, 256, 0, stream>>>(a, 2752512L);
  }
  {
    TcArgs t;
    t.s[0] = Wuk; t.d[0] = WukT;
    t.s[1] = Wuv; t.d[1] = WuvT;
    t.s[2] = Wuq; t.d[2] = WuqT;   // Wuq buffer viewed (512x2048) -> U^T
    tcastg<<<3072, 256, 0, stream>>>(t);
  }

  // ---- 2) merge1: QKV split-K x4 (640) + veffT split-K (256) = 896 blocks
  {
    JobPack3 P;
    // j0: Qprt[kc] = x_bf[:, kc*512:(kc+1)*512] @ W3chunk^T, fp32 partials.
    //     z = (z1: W3 576-row chunk, z2: k-chunk). C = Qprt + z1*576 + z2*plane.
    P.j[0] = {x_bf, W3, Qprt, 0, 512, (long)576 * 2048, 512,
              576, (long)2048 * 1152,
              512, 2048, 2048, 1152, 576, 4, 5, 16, 0};
    P.j[1] = {Wo_bf, WuvT, Vprt, 512, 0, 512, 0, 1048576, 0,
              512, 2048, 2048, 512, 512, 1, 4, 16, 0};
    P.j[2] = P.j[1];  // unused
    P.cum[0] = 0; P.cum[1] = 640; P.cum[2] = 896; P.cum[3] = 896;
    gemm_db<<<896, 256, 0, stream>>>(P);
  }
  // reduce both partial sets -> veffT (bf16) and cq/Kcat (bf16)
  vred2<<<3328, 256, 0, stream>>>(Vprt, veffT, Qprt, cq, Kcat);

  // ---- 3) merge2: q_up(256) + ZT(256) + c_qr(128) = 640 blocks (dbuf GEMM)
  {
    JobPack3 P;
    P.j[0] = {cq, WuqT, qup, 0, 0, 0, 0, 0, 0,
              512, 576, 512, 2048, 2048, 1, 16, 16, 1};
    P.j[1] = {veffT, Kcat, ZTbuf, 0, 65536, 589824, 0, 2097152, 131072,
              512, 512, 576, 1024, 1024, 16, 8, 1, 1};
    P.j[2] = {cq, Wqr_bf, cqr, 0, 0, 0, 0, 0, 0,
              512, 576, 512, 1024, 1024, 1, 8, 16, 1};
    P.cum[0] = 0; P.cum[1] = 256; P.cum[2] = 512; P.cum[3] = 640;
    gemm_db<<<640, 256, 0, stream>>>(P);
  }

  // ---- 4) merge3: q_abs = q_up_h @ W_uk_h per head, K=128 (1024 blocks,
  //          single-buffered: K=128 barely pipelines, keep 4 blocks/CU)
  {
    JobPack3 P;
    P.j[0] = {qup, WukT, Qcat, 2097152, 128, 0, 128, 9437184, 589824,
              128, 2048, 2048, 576, 512, 16, 4, 8, 1};
    P.j[1] = P.j[0];  // unused
    P.j[2] = P.j[0];  // unused
    P.cum[0] = 0; P.cum[1] = 1024; P.cum[2] = 1024; P.cum[3] = 1024;
    gemm_multi<<<1024, 256, 0, stream>>>(P);
  }

  // ---- 5) ropes: Kcat cols 512.. in place + cqr -> Qcat cols 512..
  rope_fused<<<4352, 256, 0, stream>>>(Kcat, cqr, Qcat, fcos, fsin);

  // ---- 6) split-flash attention
  attn_part<<<1280, 256, 0, stream>>>(Qcat, Kcat, ZTbuf, Opart, mlbuf, out);
  attn_merge<<<1536, 256, 0, stream>>>(Opart, mlbuf, out);
}

// Round 10
// 273.525 us; speedup vs baseline: 1.0375x; 1.0375x over previous
//
#include <hip/hip_runtime.h>

// ---------------------------------------------------------------------------
// FullMHLA: B=2, T=1024, C=2048, NH=16, NLQ=512, NLKV=512, DHR=64, HS=128.
// Round 19: R18's split-K QKV reverted (guardrail: partial-traffic cost > TLP
// gain; total 283.8 vs R17 274.9). Back to R17 dataflow, plus launch-graph
// compaction: prep_all = cast_all+tcastg fused; merge3_rope = q_abs GEMM +
// rope fused (disjoint outputs: GEMM writes Qcat cols 0..511, rope cols
// 512+). 7 -> 5 pre-attention launches. attn_part remains byte-exact R0.
// ---------------------------------------------------------------------------
#define Bv   2
#define Tv   1024
#define Cv   2048
#define NHv  16

typedef unsigned short u16;
typedef __attribute__((ext_vector_type(8))) short bf8_t;
typedef __attribute__((ext_vector_type(4))) float f4_t;
typedef __attribute__((ext_vector_type(4))) unsigned short u16x4;
typedef __attribute__((ext_vector_type(8))) unsigned short u16x8;

__device__ __forceinline__ u16 f2bf(float f) {
  union { float f; unsigned u; } v; v.f = f;
  unsigned r = v.u + 0x7fffu + ((v.u >> 16) & 1u);   // RNE
  return (u16)(r >> 16);
}
__device__ __forceinline__ float bf2f(u16 b) {
  return __uint_as_float((unsigned)b << 16);
}
__device__ __forceinline__ void glds16(const u16* gp, u16* lp) {
  __builtin_amdgcn_global_load_lds(
      (const __attribute__((address_space(1))) void*)gp,
      (__attribute__((address_space(3))) void*)lp, 16, 0, 0);
}

// ---------------------------------------------------------------------------
// Multi-job bf16 NT MFMA GEMM: C = A * B^T. 128x128 tile, BK=64, 256 thr.
// Double-buffered K-loop: stage t+1 before compute t, 1 barrier per K-step.
// ---------------------------------------------------------------------------
struct Job {
  const u16* A; const u16* B; void* C;
  long sA1, sA2, sB1, sB2, sC1, sC2;
  int K, lda, ldb, ldc, Nact, zdiv, ntx, nty, out_bf;
};
struct JobPack3 { Job j[3]; int cum[4]; };

__global__ __launch_bounds__(256) void gemm_db(JobPack3 P) {
  const int bid = blockIdx.x;
  const int ji = (bid >= P.cum[1] ? 1 : 0) + (bid >= P.cum[2] ? 1 : 0);
  const Job& J = P.j[ji];
  int local = bid - P.cum[ji];
  const int x = local % J.ntx;
  int rest = local / J.ntx;
  const int y = rest % J.nty;
  const int z = rest / J.nty;
  const int m0 = y * 128, n0 = x * 128;

  const int z1 = z / J.zdiv, z2 = z % J.zdiv;
  const u16* A = J.A + z1 * J.sA1 + z2 * J.sA2;
  const u16* B = J.B + z1 * J.sB1 + z2 * J.sB2;
  const int K = J.K, lda = J.lda, ldb = J.ldb, ldc = J.ldc, Nact = J.Nact;

  __shared__ u16 SMEM[32768];   // 2 x (As 16KB + Bs 16KB)

  const int tid = threadIdx.x, w = tid >> 6, ln = tid & 63;
  const int my = w >> 1, mx = w & 1;
  const int g = ln >> 4, m = ln & 15;

  const int sr = (ln >> 3);            // +8q +32w below
  const int nk = K >> 6;

  f4_t acc[4][4];
#pragma unroll
  for (int i = 0; i < 4; ++i)
#pragma unroll
    for (int j = 0; j < 4; ++j) acc[i][j] = (f4_t)0.f;

  // prologue: stage tile 0 into buf 0
  {
    u16* As = SMEM;
    u16* Bs = SMEM + 8192;
#pragma unroll
    for (int q = 0; q < 4; ++q) {
      int r = 32 * w + 8 * q + sr;
      int c = ((ln & 7) - r) & 7;
      glds16(&A[(long)(m0 + r) * lda + c * 8], &As[(32 * w + 8 * q) * 64]);
      glds16(&B[(long)(n0 + r) * ldb + c * 8], &Bs[(32 * w + 8 * q) * 64]);
    }
  }
  __syncthreads();

  int buf = 0;
#pragma unroll 1
  for (int t = 0; t < nk; ++t) {
    // stage t+1 into the other buffer FIRST (latency hides under MFMA below)
    if (t + 1 < nk) {
      const int k0 = (t + 1) * 64;
      u16* As = SMEM + (buf ^ 1) * 16384;
      u16* Bs = As + 8192;
#pragma unroll
      for (int q = 0; q < 4; ++q) {
        int r = 32 * w + 8 * q + sr;
        int c = ((ln & 7) - r) & 7;
        glds16(&A[(long)(m0 + r) * lda + k0 + c * 8],
               &As[(32 * w + 8 * q) * 64]);
        glds16(&B[(long)(n0 + r) * ldb + k0 + c * 8],
               &Bs[(32 * w + 8 * q) * 64]);
      }
    }
    // compute tile t from buf (data guaranteed by previous barrier)
    {
      const u16* As = SMEM + buf * 16384;
      const u16* Bs = As + 8192;
#pragma unroll
      for (int kh = 0; kh < 2; ++kh) {
        bf8_t af[4], bg[4];
#pragma unroll
        for (int mt = 0; mt < 4; ++mt) {
          int row = my * 64 + mt * 16 + m;
          af[mt] = *(const bf8_t*)&As[row * 64 + (((kh * 4 + g) + row) & 7) * 8];
        }
#pragma unroll
        for (int nt = 0; nt < 4; ++nt) {
          int row = mx * 64 + nt * 16 + m;
          bg[nt] = *(const bf8_t*)&Bs[row * 64 + (((kh * 4 + g) + row) & 7) * 8];
        }
#pragma unroll
        for (int mt = 0; mt < 4; ++mt)
#pragma unroll
          for (int nt = 0; nt < 4; ++nt)
            acc[mt][nt] = __builtin_amdgcn_mfma_f32_16x16x32_bf16(
                af[mt], bg[nt], acc[mt][nt], 0, 0, 0);
      }
    }
    __syncthreads();   // drains stage(t+1) loads; joins readers of buf
    buf ^= 1;
  }

  if (J.out_bf) {
    u16* Es = SMEM + w * 4096;
#pragma unroll
    for (int mt = 0; mt < 4; ++mt)
#pragma unroll
      for (int nt = 0; nt < 4; ++nt)
#pragma unroll
        for (int r = 0; r < 4; ++r) {
          int row = mt * 16 + g * 4 + r;
          int col = nt * 16 + m;
          Es[row * 64 + (((col >> 3) + row) & 7) * 8 + (col & 7)] =
              f2bf(acc[mt][nt][r]);
        }
    __syncthreads();
    u16* C = (u16*)J.C + z1 * J.sC1 + z2 * J.sC2;
    const long rowbase = (long)(m0 + my * 64 + ln) * ldc + n0 + mx * 64;
#pragma unroll
    for (int c = 0; c < 8; ++c) {
      if (n0 + mx * 64 + c * 8 < Nact) {
        u16x8 v = *(const u16x8*)&Es[ln * 64 + ((c + ln) & 7) * 8];
        *(u16x8*)&C[rowbase + c * 8] = v;
      }
    }
  } else {
    float* C = (float*)J.C + z1 * J.sC1 + z2 * J.sC2;
#pragma unroll
    for (int mt = 0; mt < 4; ++mt)
#pragma unroll
      for (int nt = 0; nt < 4; ++nt)
#pragma unroll
        for (int r = 0; r < 4; ++r) {
          int row = m0 + my * 64 + mt * 16 + g * 4 + r;
          int col = n0 + mx * 64 + nt * 16 + m;
          if (col < Nact) C[(long)row * ldc + col] = acc[mt][nt][r];
        }
  }
}

// ---------------------------------------------------------------------------
// Split-flash attention, pass 1. (Byte-exact R0 baseline.)
// ---------------------------------------------------------------------------
__global__ __launch_bounds__(256, 3) void attn_part(
    const u16* __restrict__ Qcat,   // (B,NH,T,576)
    const u16* __restrict__ Kcat,   // (B,T,576) roped
    const u16* __restrict__ ZT,     // (B,NH,128,1024)
    float* __restrict__ Opart,      // (1280,64,128)
    float* __restrict__ ml,         // (1280,2,64)
    float* __restrict__ out) {      // (B,T,2048)
  const int x = blockIdx.x;          // 1280
  const int bh = x & 31, item = x >> 5;  // 0..39
  const int b = bh >> 4, h = bh & 15;
  // heavy (2-s-tile) items first, 8 light items last
  static const int qtab[40] = {2,3,4,5,6,6,7,7,8,8,9,9,10,10,10,11,11,11,
                               12,12,12,13,13,13,14,14,14,14,15,15,15,15,
                               0,1,4,5,8,9,12,13};
  static const int ctab[40] = {0,0,0,0,0,1,0,1,0,1,0,1,0,1,2,0,1,2,
                               0,1,2,0,1,2,0,1,2,3,0,1,2,3,
                               0,0,1,1,2,2,3,3};
  const int qt = qtab[item], ch = ctab[item];
  const int ns = (qt >> 1) + 1;             // causal s-tiles for this q-tile
  const int s0t = 2 * ch, s1t = min(2 * ch + 2, ns);
  const bool full = (ch == 0) && (qt <= 3);

  __shared__ u16 As[4096];    // Q-tile 64x64
  __shared__ u16 Bs[8192];    // K/ZT-tile 128x64
  __shared__ u16 Ps[8192];    // P 64x128, chunk-swizzle mod 16

  const int tid = threadIdx.x, w = tid >> 6, ln = tid & 63;
  const int g = ln >> 4, m = ln & 15;

  const u16* Qb = Qcat + (long)bh * 589824 + (long)qt * 64 * 576;
  const u16* Kb = Kcat + (long)b * 589824;
  const u16* Zb = ZT + (long)bh * 131072;

  f4_t O[8];
#pragma unroll
  for (int j = 0; j < 8; ++j) O[j] = (f4_t)0.f;
  float mrow[4], lrow[4];
#pragma unroll
  for (int r = 0; r < 4; ++r) { mrow[r] = -3e38f; lrow[r] = 0.f; }

  const float scale = 0.07216878364870322f;  // 1/sqrt(192)

  for (int st = s0t; st < s1t; ++st) {
    f4_t S[8];
#pragma unroll
    for (int j = 0; j < 8; ++j) S[j] = (f4_t)0.f;

    // ---- QK: 9 BK-iters over K=576
    for (int k0 = 0; k0 < 576; k0 += 64) {
#pragma unroll
      for (int q = 0; q < 2; ++q) {
        int r = 16 * w + 8 * q + (ln >> 3);
        int c = ((ln & 7) - r) & 7;
        glds16(&Qb[(long)r * 576 + k0 + c * 8], &As[(16 * w + 8 * q) * 64]);
      }
#pragma unroll
      for (int q = 0; q < 4; ++q) {
        int r = 32 * w + 8 * q + (ln >> 3);
        int c = ((ln & 7) - r) & 7;
        glds16(&Kb[(long)(st * 128 + r) * 576 + k0 + c * 8],
               &Bs[(32 * w + 8 * q) * 64]);
      }
      __syncthreads();
#pragma unroll
      for (int kh = 0; kh < 2; ++kh) {
        int qrow = 16 * w + m;
        bf8_t af = *(const bf8_t*)&As[qrow * 64 + (((kh * 4 + g) + qrow) & 7) * 8];
#pragma unroll
        for (int nt = 0; nt < 8; ++nt) {
          int row = nt * 16 + m;
          bf8_t bb = *(const bf8_t*)&Bs[row * 64 + (((kh * 4 + g) + row) & 7) * 8];
          S[nt] = __builtin_amdgcn_mfma_f32_16x16x32_bf16(af, bb, S[nt], 0, 0, 0);
        }
      }
      __syncthreads();
    }

    // ---- scale + causal mask (diag s-tile only)
    const bool diag = (st == (qt >> 1));
#pragma unroll
    for (int nt = 0; nt < 8; ++nt)
#pragma unroll
      for (int r = 0; r < 4; ++r) {
        float v = S[nt][r] * scale;
        if (diag &&
            (st * 128 + nt * 16 + m) > (qt * 64 + 16 * w + g * 4 + r))
          v = -3e38f;
        S[nt][r] = v;
      }

    // ---- online softmax (rows wave-local; 16-lane butterflies over m)
#pragma unroll
    for (int r = 0; r < 4; ++r) {
      float mx = S[0][r];
#pragma unroll
      for (int nt = 1; nt < 8; ++nt) mx = fmaxf(mx, S[nt][r]);
#pragma unroll
      for (int o = 1; o < 16; o <<= 1) mx = fmaxf(mx, __shfl_xor(mx, o, 64));
      float mn = fmaxf(mrow[r], mx);
      float al = __expf(mrow[r] - mn);
      mrow[r] = mn;
      float rs = 0.f;
#pragma unroll
      for (int nt = 0; nt < 8; ++nt) {
        float p = __expf(S[nt][r] - mn);
        S[nt][r] = p;
        rs += p;
      }
#pragma unroll
      for (int o = 1; o < 16; o <<= 1) rs += __shfl_xor(rs, o, 64);
      lrow[r] = lrow[r] * al + rs;
#pragma unroll
      for (int nt = 0; nt < 8; ++nt) O[nt][r] *= al;
    }

    // ---- P~ -> LDS (wave-local 16 rows; mod-16 chunk swizzle)
#pragma unroll
    for (int nt = 0; nt < 8; ++nt) {
      int colc = nt * 2 + (m >> 3), cole = m & 7;
#pragma unroll
      for (int r = 0; r < 4; ++r) {
        int row = 16 * w + g * 4 + r;
        Ps[row * 128 + ((colc + row) & 15) * 8 + cole] = f2bf(S[nt][r]);
      }
    }

    // ---- PV: O += P~ . ZT-sliceT (K=128, 2 BK-iters)
#pragma unroll
    for (int kb = 0; kb < 2; ++kb) {
      __syncthreads();  // Bs reuse guard
#pragma unroll
      for (int q = 0; q < 4; ++q) {
        int r = 32 * w + 8 * q + (ln >> 3);
        int c = ((ln & 7) - r) & 7;
        glds16(&Zb[(long)r * 1024 + st * 128 + kb * 64 + c * 8],
               &Bs[(32 * w + 8 * q) * 64]);
      }
      __syncthreads();
#pragma unroll
      for (int kh = 0; kh < 2; ++kh) {
        int qrow = 16 * w + m;
        int chk = kb * 8 + kh * 4 + g;
        bf8_t af = *(const bf8_t*)&Ps[qrow * 128 + ((chk + qrow) & 15) * 8];
#pragma unroll
        for (int nt = 0; nt < 8; ++nt) {
          int row = nt * 16 + m;
          bf8_t bb = *(const bf8_t*)&Bs[row * 64 + (((kh * 4 + g) + row) & 7) * 8];
          O[nt] = __builtin_amdgcn_mfma_f32_16x16x32_bf16(af, bb, O[nt], 0, 0, 0);
        }
      }
    }
    __syncthreads();  // protect As/Bs/Ps for next s-tile
  }

  if (full) {
    // ---- direct write: y = O/l (block saw the whole causal range)
    float* ob = out + ((long)b * Tv + qt * 64 + 16 * w) * 2048 + h * 128;
#pragma unroll
    for (int r = 0; r < 4; ++r) {
      float inv = 1.0f / lrow[r];
#pragma unroll
      for (int nt = 0; nt < 8; ++nt)
        ob[(long)(g * 4 + r) * 2048 + nt * 16 + m] = O[nt][r] * inv;
    }
  } else {
    // ---- emit partials: Opart (unnormalized), ml (m, l per row)
    float* Ob = Opart + (long)x * 8192;
#pragma unroll
    for (int r = 0; r < 4; ++r) {
      int row = 16 * w + g * 4 + r;
#pragma unroll
      for (int nt = 0; nt < 8; ++nt)
        Ob[(long)row * 128 + nt * 16 + m] = O[nt][r];
      if (m == 0) {
        ml[(long)x * 128 + row] = mrow[r];
        ml[(long)x * 128 + 64 + row] = lrow[r];
      }
    }
  }
}

// ---------------------------------------------------------------------------
// Split-flash pass 2: merge partials for qt>=4, write y fp32.
// Grid 1536 = (12 qt x 32 bh) x 4 row-groups; 256 thr = 8 rows x 32 float4.
// ---------------------------------------------------------------------------
__global__ __launch_bounds__(256) void attn_merge(
    const float* __restrict__ Opart, const float* __restrict__ ml,
    float* __restrict__ out) {
  const int i = blockIdx.x;
  const int rg = i & 3;                // 16-row group
  const int combo = i >> 2;            // 0..383
  const int bh = combo & 31, qt = 4 + (combo >> 5);  // 4..15
  const int b = bh >> 4, h = bh & 15;
  static const int NCH[16] = {1,1,1,1,2,2,2,2,3,3,3,3,4,4,4,4};
  static const int ITEM[64] = {
      32,0,0,0,  33,0,0,0,  0,0,0,0,   1,0,0,0,
      2,34,0,0,  3,35,0,0,  4,5,0,0,   6,7,0,0,
      8,9,36,0,  10,11,37,0, 12,13,14,0, 15,16,17,0,
      18,19,20,38, 21,22,23,39, 24,25,26,27, 28,29,30,31};
  const int nch = NCH[qt];
  const int r = threadIdx.x >> 5, c4 = threadIdx.x & 31;
  float* ob = out + ((long)b * Tv + qt * 64 + rg * 16) * 2048 + h * 128;
#pragma unroll
  for (int rr = 0; rr < 2; ++rr) {
    const int lrow = r + rr * 8;          // 0..15 within group
    const int row = rg * 16 + lrow;       // 0..63 absolute
    float M = -3e38f, mi[4], li[4];
    for (int k = 0; k < nch; ++k) {
      long p = (long)ITEM[qt * 4 + k] * 32 + bh;
      mi[k] = ml[p * 128 + row];
      li[k] = ml[p * 128 + 64 + row];
      M = fmaxf(M, mi[k]);
    }
    float L = 0.f;
    float ax = 0.f, ay = 0.f, az = 0.f, aw = 0.f;
    for (int k = 0; k < nch; ++k) {
      long p = (long)ITEM[qt * 4 + k] * 32 + bh;
      float e = __expf(mi[k] - M);
      L += li[k] * e;
      float4 v = *(const float4*)&Opart[p * 8192 + (long)row * 128 + c4 * 4];
      ax += v.x * e; ay += v.y * e; az += v.z * e; aw += v.w * e;
    }
    const float inv = 1.0f / L;
    float4 o4 = {ax * inv, ay * inv, az * inv, aw * inv};
    *(float4*)&ob[(long)lrow * 2048 + c4 * 4] = o4;
  }
}

// ---------------------------------------------------------------------------
// prep_all: fused (a) fp32->bf16 casts (5 segments) + Wkr pad into W3
// [blocks 0..11135] and (b) 3 transpose-cast jobs [blocks 11136..14207]:
// job0 Wuk(2048x512)->WukT, job1 Wuv->WuvT, job2 Wuq viewed(512x2048)->WuqT.
// ---------------------------------------------------------------------------
struct PrepArgs {
  const float* src[5];
  u16* dst[5];
  long cum[6];
  const float* wkr;
  u16* w3;
  const float* ts[3];
  u16* td[3];
};
__global__ __launch_bounds__(256) void prep_all(PrepArgs a) {
  __shared__ u16 sm[32][33];
  const int bid = blockIdx.x;
  if (bid < 11136) {
    long i = (long)bid * 256 + threadIdx.x;
    if (i < 2752512) {
      int seg = 0;
      while (i >= a.cum[seg + 1]) ++seg;
      long j = i - a.cum[seg];
      float4 vv = ((const float4*)a.src[seg])[j];
      u16x4 o;
      o[0] = f2bf(vv.x); o[1] = f2bf(vv.y); o[2] = f2bf(vv.z); o[3] = f2bf(vv.w);
      ((u16x4*)a.dst[seg])[j] = o;
    } else {
      long j = i - 2752512;  // < 98304
      u16x4* W4 = (u16x4*)a.w3;
      if (j < 32768) {
        float4 vv = ((const float4*)a.wkr)[j];
        u16x4 o;
        o[0] = f2bf(vv.x); o[1] = f2bf(vv.y); o[2] = f2bf(vv.z); o[3] = f2bf(vv.w);
        W4[557056 + j] = o;                    // rows 1088..1151
      } else if (j < 65536) {
        W4[262144 + (j - 32768)] = (u16x4)0;   // rows 512..575
      } else {
        W4[589824 + (j - 65536)] = (u16x4)0;   // rows 1152..1215
      }
    }
  } else {
    const int t = bid - 11136;           // 0..3071
    const int job = t >> 10, tt = t & 1023;
    const float* in = a.ts[job];
    u16* out = a.td[job];
    const int R = (job == 2) ? 512 : 2048;
    const int C = (job == 2) ? 2048 : 512;
    const int xt = (job == 2) ? 64 : 16;   // C/32 tiles along columns
    const int x = tt % xt, y = tt / xt;
    const int c0 = x * 32, r0 = y * 32;
    const int tx = threadIdx.x & 31, ty = threadIdx.x >> 5;
    for (int i = ty; i < 32; i += 8)
      sm[i][tx] = f2bf(in[(long)(r0 + i) * C + c0 + tx]);
    __syncthreads();
    for (int i = ty; i < 32; i += 8)
      out[(long)(c0 + i) * R + r0 + tx] = sm[tx][i];
  }
}

// ---------------------------------------------------------------------------
// merge3_rope: fused (a) q_abs GEMM [blocks 0..1023]: per head h,
// Qcat[b,h,:,0:512] = qup[b,:,h*128:(h+1)*128] @ WukT_h^T (K=128, 128x128
// tiles, single-buffered, bf16 out) and (b) ropes [blocks 1024..5375]:
// Kcat cols 512.. in place + rope+scatter cqr -> Qcat cols 512...
// Outputs disjoint (GEMM: Qcat cols 0..511; rope: cols 512..575 / Kcat).
// ---------------------------------------------------------------------------
__global__ __launch_bounds__(256) void merge3_rope(
    const u16* __restrict__ qup, const u16* __restrict__ WukT,
    u16* __restrict__ Qcat, u16* __restrict__ Kcat,
    const u16* __restrict__ cqr,
    const float* __restrict__ cosf, const float* __restrict__ sinf) {
  __shared__ u16 SMEM[16384];
  const int bid = blockIdx.x;
  if (bid < 1024) {
    // ---- q_abs GEMM: ntx=4, nty=8, z = b*16 + h
    const int x = bid & 3;
    int rest = bid >> 2;
    const int y = rest & 7;
    const int z = rest >> 3;             // 0..31
    const int z1 = z >> 4, z2 = z & 15;  // batch, head
    const u16* A = qup + (long)z1 * 2097152 + z2 * 128;
    const u16* B = WukT + z2 * 128;
    u16* C = Qcat + (long)z1 * 9437184 + (long)z2 * 589824;
    const int m0 = y * 128, n0 = x * 128;
    u16* As = SMEM;
    u16* Bs = SMEM + 8192;

    const int tid = threadIdx.x, w = tid >> 6, ln = tid & 63;
    const int my = w >> 1, mx = w & 1;
    const int g = ln >> 4, m = ln & 15;

    f4_t acc[4][4];
#pragma unroll
    for (int i = 0; i < 4; ++i)
#pragma unroll
      for (int j = 0; j < 4; ++j) acc[i][j] = (f4_t)0.f;

    for (int k0 = 0; k0 < 128; k0 += 64) {
#pragma unroll
      for (int q = 0; q < 4; ++q) {
        int r = 32 * w + 8 * q + (ln >> 3);
        int c = ((ln & 7) - r) & 7;
        glds16(&A[(long)(m0 + r) * 2048 + k0 + c * 8],
               &As[(32 * w + 8 * q) * 64]);
        glds16(&B[(long)(n0 + r) * 2048 + k0 + c * 8],
               &Bs[(32 * w + 8 * q) * 64]);
      }
      __syncthreads();
#pragma unroll
      for (int kh = 0; kh < 2; ++kh) {
        bf8_t af[4], bg[4];
#pragma unroll
        for (int mt = 0; mt < 4; ++mt) {
          int row = my * 64 + mt * 16 + m;
          af[mt] = *(const bf8_t*)&As[row * 64 + (((kh * 4 + g) + row) & 7) * 8];
        }
#pragma unroll
        for (int nt = 0; nt < 4; ++nt) {
          int row = mx * 64 + nt * 16 + m;
          bg[nt] = *(const bf8_t*)&Bs[row * 64 + (((kh * 4 + g) + row) & 7) * 8];
        }
#pragma unroll
        for (int mt = 0; mt < 4; ++mt)
#pragma unroll
          for (int nt = 0; nt < 4; ++nt)
            acc[mt][nt] = __builtin_amdgcn_mfma_f32_16x16x32_bf16(
                af[mt], bg[nt], acc[mt][nt], 0, 0, 0);
      }
      __syncthreads();
    }

    u16* Es = SMEM + w * 4096;
#pragma unroll
    for (int mt = 0; mt < 4; ++mt)
#pragma unroll
      for (int nt = 0; nt < 4; ++nt)
#pragma unroll
        for (int r = 0; r < 4; ++r) {
          int row = mt * 16 + g * 4 + r;
          int col = nt * 16 + m;
          Es[row * 64 + (((col >> 3) + row) & 7) * 8 + (col & 7)] =
              f2bf(acc[mt][nt][r]);
        }
    __syncthreads();
    const long rowbase = (long)(m0 + my * 64 + ln) * 576 + n0 + mx * 64;
#pragma unroll
    for (int c = 0; c < 8; ++c) {
      u16x8 v = *(const u16x8*)&Es[ln * 64 + ((c + ln) & 7) * 8];
      *(u16x8*)&C[rowbase + c * 8] = v;
    }
  } else {
    // ---- ropes
    int idx = (bid - 1024) * 256 + threadIdx.x;  // < 1,114,112
    if (idx < 65536) {
      int i = idx & 31, t = (idx >> 5) & 1023, b = idx >> 15;
      float c = cosf[t * 32 + i], s = sinf[t * 32 + i];
      u16* p = Kcat + ((long)(b * Tv + t) * 576 + 512 + 2 * i);
      float re = bf2f(p[0]), im = bf2f(p[1]);
      p[0] = f2bf(re * c - im * s);
      p[1] = f2bf(re * s + im * c);
    } else {
      int j = idx - 65536;  // < 1,048,576
      int i = j & 31, h = (j >> 5) & 15, t = (j >> 9) & 1023, b = j >> 19;
      float c = cosf[t * 32 + i], s = sinf[t * 32 + i];
      const u16* src = cqr + ((long)(b * Tv + t) * 1024 + h * 64 + 2 * i);
      float re = bf2f(src[0]), im = bf2f(src[1]);
      u16* dst = Qcat + (((long)(b * NHv + h) * Tv + t) * 576 + 512 + 2 * i);
      dst[0] = f2bf(re * c - im * s);
      dst[1] = f2bf(re * s + im * c);
    }
  }
}

// Reduce 4 fp32 split-K partials (2048x512) -> bf16 veffT
__global__ void vred(const float* __restrict__ P, u16* __restrict__ veffT) {
  int i = blockIdx.x * 256 + threadIdx.x;  // < 262144
  float4 v0 = ((const float4*)P)[i];
  float4 v1 = ((const float4*)P)[262144 + i];
  float4 v2 = ((const float4*)P)[524288 + i];
  float4 v3 = ((const float4*)P)[786432 + i];
  u16x4 o;
  o[0] = f2bf(v0.x + v1.x + v2.x + v3.x);
  o[1] = f2bf(v0.y + v1.y + v2.y + v3.y);
  o[2] = f2bf(v0.z + v1.z + v2.z + v3.z);
  o[3] = f2bf(v0.w + v1.w + v2.w + v3.w);
  ((u16x4*)veffT)[i] = o;
}

// ---------------------------------------------------------------------------
// kernel_launch
// ---------------------------------------------------------------------------
extern "C" void kernel_launch(void* const* d_in, const int* in_sizes, int n_in,
                              void* d_out, int out_size, void* d_ws,
                              size_t ws_size, hipStream_t stream) {
  const float* x    = (const float*)d_in[0];
  const float* fcos = (const float*)d_in[1];
  const float* fsin = (const float*)d_in[2];
  const float* Wdq  = (const float*)d_in[3];
  const float* Wuq  = (const float*)d_in[4];
  const float* Wdkv = (const float*)d_in[5];
  const float* Wuk  = (const float*)d_in[6];
  const float* Wuv  = (const float*)d_in[7];
  const float* Wqr  = (const float*)d_in[8];
  const float* Wkr  = (const float*)d_in[9];
  const float* Wo   = (const float*)d_in[10];
  float* out = (float*)d_out;

  // ---- workspace carve-up (u16 units; total ~154 MB < 256 MiB)
  u16* ws = (u16*)d_ws;
  u16* cq     = ws;                  // (2048x576)        1,179,648
  u16* Kcat   = cq + 1179648;        // (B,T,576)         1,179,648
  u16* veffT  = Kcat + 1179648;      // (2048x512)        1,048,576
  u16* Qcat   = veffT + 1048576;     // (B,NH,T,576)     18,874,368
  u16* W3     = Qcat + 18874368;     // (1216x2048)       2,490,368
  u16* x_bf   = W3 + 2490368;        //                   4,194,304
  u16* Wqr_bf = x_bf + 4194304;      //                     524,288
  u16* WuqT   = Wqr_bf + 524288;     // (2048x512) = U^T  1,048,576
  u16* Wo_bf  = WuqT + 1048576;      //                   4,194,304
  u16* WukT   = Wo_bf + 4194304;     // (512x2048)        1,048,576
  u16* WuvT   = WukT + 1048576;      // (512x2048)        1,048,576
  u16* cqr    = WuvT + 1048576;      // (B,T,1024)        2,097,152
  u16* qup    = cqr + 2097152;       // (2048x2048)       4,194,304
  u16* ZTbuf  = qup + 4194304;       // (B,NH,128,1024)   4,194,304
  float* Vprt  = (float*)(ZTbuf + 4194304);   // 4x(2048x512) fp32
  float* Opart = Vprt + 4194304;              // 1280x64x128 fp32
  float* mlbuf = Opart + 10485760;            // 1280x2x64 fp32

  // ---- 1) prep: casts (+Wkr pad) + 3 transpose-casts, one launch
  {
    PrepArgs a;
    a.src[0] = x;    a.dst[0] = x_bf;
    a.src[1] = Wdq;  a.dst[1] = W3;
    a.src[2] = Wdkv; a.dst[2] = W3 + 576 * 2048;
    a.src[3] = Wqr;  a.dst[3] = Wqr_bf;
    a.src[4] = Wo;   a.dst[4] = Wo_bf;
    a.cum[0] = 0;        a.cum[1] = 1048576; a.cum[2] = 1310720;
    a.cum[3] = 1572864;  a.cum[4] = 1703936; a.cum[5] = 2752512;
    a.wkr = Wkr; a.w3 = W3;
    a.ts[0] = Wuk; a.td[0] = WukT;
    a.ts[1] = Wuv; a.td[1] = WuvT;
    a.ts[2] = Wuq; a.td[2] = WuqT;   // Wuq viewed (512x2048) -> U^T
    prep_all<<<14208, 256, 0, stream>>>(a);
  }

  // ---- 2) merge1: QKV(160) + veffT split-K(256) = 416 blocks (dbuf GEMM)
  {
    JobPack3 P;
    P.j[0] = {x_bf, W3, cq, 0, 0, (long)576 * 2048, 0, 1179648, 0,
              2048, 2048, 2048, 576, 576, 1, 5, 16, 1};
    P.j[1] = {Wo_bf, WuvT, Vprt, 512, 0, 512, 0, 1048576, 0,
              512, 2048, 2048, 512, 512, 1, 4, 16, 0};
    P.j[2] = P.j[1];  // unused
    P.cum[0] = 0; P.cum[1] = 160; P.cum[2] = 416; P.cum[3] = 416;
    gemm_db<<<416, 256, 0, stream>>>(P);
  }
  vred<<<1024, 256, 0, stream>>>(Vprt, veffT);

  // ---- 3) merge2: q_up(256) + ZT(256) + c_qr(128) = 640 blocks (dbuf GEMM)
  {
    JobPack3 P;
    P.j[0] = {cq, WuqT, qup, 0, 0, 0, 0, 0, 0,
              512, 576, 512, 2048, 2048, 1, 16, 16, 1};
    P.j[1] = {veffT, Kcat, ZTbuf, 0, 65536, 589824, 0, 2097152, 131072,
              512, 512, 576, 1024, 1024, 16, 8, 1, 1};
    P.j[2] = {cq, Wqr_bf, cqr, 0, 0, 0, 0, 0, 0,
              512, 576, 512, 1024, 1024, 1, 8, 16, 1};
    P.cum[0] = 0; P.cum[1] = 256; P.cum[2] = 512; P.cum[3] = 640;
    gemm_db<<<640, 256, 0, stream>>>(P);
  }

  // ---- 4) merge3 (q_abs, 1024 blocks) + ropes (4352 blocks), one launch
  merge3_rope<<<5376, 256, 0, stream>>>(qup, WukT, Qcat, Kcat, cqr,
                                        fcos, fsin);

  // ---- 5) split-flash attention
  attn_part<<<1280, 256, 0, stream>>>(Qcat, Kcat, ZTbuf, Opart, mlbuf, out);
  attn_merge<<<1536, 256, 0, stream>>>(Opart, mlbuf, out);
}

// Round 11
// 270.373 us; speedup vs baseline: 1.0496x; 1.0117x over previous
//
#include <hip/hip_runtime.h>

// ---------------------------------------------------------------------------
// FullMHLA: B=2, T=1024, C=2048, NH=16, NLQ=512, NLKV=512, DHR=64, HS=128.
// Round 20: R19 + T1 XCD-aware bijective block swizzle on the GEMM launches
// (gemm_db, merge3_rope GEMM half). Consecutive logical tiles share A/B
// panels; default dispatch round-robins them across 8 XCD-private L2s ->
// refetch. Swizzle wgid=(bid&7)*cpx+(bid>>3) gives each XCD a contiguous
// run (nwg%8==0: 416/640/1024). attn_part frozen (byte-exact R0).
// ---------------------------------------------------------------------------
#define Bv   2
#define Tv   1024
#define Cv   2048
#define NHv  16

typedef unsigned short u16;
typedef __attribute__((ext_vector_type(8))) short bf8_t;
typedef __attribute__((ext_vector_type(4))) float f4_t;
typedef __attribute__((ext_vector_type(4))) unsigned short u16x4;
typedef __attribute__((ext_vector_type(8))) unsigned short u16x8;

__device__ __forceinline__ u16 f2bf(float f) {
  union { float f; unsigned u; } v; v.f = f;
  unsigned r = v.u + 0x7fffu + ((v.u >> 16) & 1u);   // RNE
  return (u16)(r >> 16);
}
__device__ __forceinline__ float bf2f(u16 b) {
  return __uint_as_float((unsigned)b << 16);
}
__device__ __forceinline__ void glds16(const u16* gp, u16* lp) {
  __builtin_amdgcn_global_load_lds(
      (const __attribute__((address_space(1))) void*)gp,
      (__attribute__((address_space(3))) void*)lp, 16, 0, 0);
}

// ---------------------------------------------------------------------------
// Multi-job bf16 NT MFMA GEMM: C = A * B^T. 128x128 tile, BK=64, 256 thr.
// Double-buffered K-loop: stage t+1 before compute t, 1 barrier per K-step.
// XCD-aware bijective swizzle on blockIdx (launch grid must be %8 == 0).
// ---------------------------------------------------------------------------
struct Job {
  const u16* A; const u16* B; void* C;
  long sA1, sA2, sB1, sB2, sC1, sC2;
  int K, lda, ldb, ldc, Nact, zdiv, ntx, nty, out_bf;
};
struct JobPack3 { Job j[3]; int cum[4]; };

__global__ __launch_bounds__(256) void gemm_db(JobPack3 P) {
  // T1: XCD-aware bijective remap (8 XCDs; nwg = cum[3] is %8==0)
  const int nwg = P.cum[3];
  const int cpx = nwg >> 3;
  const int bid = (blockIdx.x & 7) * cpx + (blockIdx.x >> 3);
  const int ji = (bid >= P.cum[1] ? 1 : 0) + (bid >= P.cum[2] ? 1 : 0);
  const Job& J = P.j[ji];
  int local = bid - P.cum[ji];
  const int x = local % J.ntx;
  int rest = local / J.ntx;
  const int y = rest % J.nty;
  const int z = rest / J.nty;
  const int m0 = y * 128, n0 = x * 128;

  const int z1 = z / J.zdiv, z2 = z % J.zdiv;
  const u16* A = J.A + z1 * J.sA1 + z2 * J.sA2;
  const u16* B = J.B + z1 * J.sB1 + z2 * J.sB2;
  const int K = J.K, lda = J.lda, ldb = J.ldb, ldc = J.ldc, Nact = J.Nact;

  __shared__ u16 SMEM[32768];   // 2 x (As 16KB + Bs 16KB)

  const int tid = threadIdx.x, w = tid >> 6, ln = tid & 63;
  const int my = w >> 1, mx = w & 1;
  const int g = ln >> 4, m = ln & 15;

  const int sr = (ln >> 3);            // +8q +32w below
  const int nk = K >> 6;

  f4_t acc[4][4];
#pragma unroll
  for (int i = 0; i < 4; ++i)
#pragma unroll
    for (int j = 0; j < 4; ++j) acc[i][j] = (f4_t)0.f;

  // prologue: stage tile 0 into buf 0
  {
    u16* As = SMEM;
    u16* Bs = SMEM + 8192;
#pragma unroll
    for (int q = 0; q < 4; ++q) {
      int r = 32 * w + 8 * q + sr;
      int c = ((ln & 7) - r) & 7;
      glds16(&A[(long)(m0 + r) * lda + c * 8], &As[(32 * w + 8 * q) * 64]);
      glds16(&B[(long)(n0 + r) * ldb + c * 8], &Bs[(32 * w + 8 * q) * 64]);
    }
  }
  __syncthreads();

  int buf = 0;
#pragma unroll 1
  for (int t = 0; t < nk; ++t) {
    // stage t+1 into the other buffer FIRST (latency hides under MFMA below)
    if (t + 1 < nk) {
      const int k0 = (t + 1) * 64;
      u16* As = SMEM + (buf ^ 1) * 16384;
      u16* Bs = As + 8192;
#pragma unroll
      for (int q = 0; q < 4; ++q) {
        int r = 32 * w + 8 * q + sr;
        int c = ((ln & 7) - r) & 7;
        glds16(&A[(long)(m0 + r) * lda + k0 + c * 8],
               &As[(32 * w + 8 * q) * 64]);
        glds16(&B[(long)(n0 + r) * ldb + k0 + c * 8],
               &Bs[(32 * w + 8 * q) * 64]);
      }
    }
    // compute tile t from buf (data guaranteed by previous barrier)
    {
      const u16* As = SMEM + buf * 16384;
      const u16* Bs = As + 8192;
#pragma unroll
      for (int kh = 0; kh < 2; ++kh) {
        bf8_t af[4], bg[4];
#pragma unroll
        for (int mt = 0; mt < 4; ++mt) {
          int row = my * 64 + mt * 16 + m;
          af[mt] = *(const bf8_t*)&As[row * 64 + (((kh * 4 + g) + row) & 7) * 8];
        }
#pragma unroll
        for (int nt = 0; nt < 4; ++nt) {
          int row = mx * 64 + nt * 16 + m;
          bg[nt] = *(const bf8_t*)&Bs[row * 64 + (((kh * 4 + g) + row) & 7) * 8];
        }
#pragma unroll
        for (int mt = 0; mt < 4; ++mt)
#pragma unroll
          for (int nt = 0; nt < 4; ++nt)
            acc[mt][nt] = __builtin_amdgcn_mfma_f32_16x16x32_bf16(
                af[mt], bg[nt], acc[mt][nt], 0, 0, 0);
      }
    }
    __syncthreads();   // drains stage(t+1) loads; joins readers of buf
    buf ^= 1;
  }

  if (J.out_bf) {
    u16* Es = SMEM + w * 4096;
#pragma unroll
    for (int mt = 0; mt < 4; ++mt)
#pragma unroll
      for (int nt = 0; nt < 4; ++nt)
#pragma unroll
        for (int r = 0; r < 4; ++r) {
          int row = mt * 16 + g * 4 + r;
          int col = nt * 16 + m;
          Es[row * 64 + (((col >> 3) + row) & 7) * 8 + (col & 7)] =
              f2bf(acc[mt][nt][r]);
        }
    __syncthreads();
    u16* C = (u16*)J.C + z1 * J.sC1 + z2 * J.sC2;
    const long rowbase = (long)(m0 + my * 64 + ln) * ldc + n0 + mx * 64;
#pragma unroll
    for (int c = 0; c < 8; ++c) {
      if (n0 + mx * 64 + c * 8 < Nact) {
        u16x8 v = *(const u16x8*)&Es[ln * 64 + ((c + ln) & 7) * 8];
        *(u16x8*)&C[rowbase + c * 8] = v;
      }
    }
  } else {
    float* C = (float*)J.C + z1 * J.sC1 + z2 * J.sC2;
#pragma unroll
    for (int mt = 0; mt < 4; ++mt)
#pragma unroll
      for (int nt = 0; nt < 4; ++nt)
#pragma unroll
        for (int r = 0; r < 4; ++r) {
          int row = m0 + my * 64 + mt * 16 + g * 4 + r;
          int col = n0 + mx * 64 + nt * 16 + m;
          if (col < Nact) C[(long)row * ldc + col] = acc[mt][nt][r];
        }
  }
}

// ---------------------------------------------------------------------------
// Split-flash attention, pass 1. (Byte-exact R0 baseline.)
// ---------------------------------------------------------------------------
__global__ __launch_bounds__(256, 3) void attn_part(
    const u16* __restrict__ Qcat,   // (B,NH,T,576)
    const u16* __restrict__ Kcat,   // (B,T,576) roped
    const u16* __restrict__ ZT,     // (B,NH,128,1024)
    float* __restrict__ Opart,      // (1280,64,128)
    float* __restrict__ ml,         // (1280,2,64)
    float* __restrict__ out) {      // (B,T,2048)
  const int x = blockIdx.x;          // 1280
  const int bh = x & 31, item = x >> 5;  // 0..39
  const int b = bh >> 4, h = bh & 15;
  // heavy (2-s-tile) items first, 8 light items last
  static const int qtab[40] = {2,3,4,5,6,6,7,7,8,8,9,9,10,10,10,11,11,11,
                               12,12,12,13,13,13,14,14,14,14,15,15,15,15,
                               0,1,4,5,8,9,12,13};
  static const int ctab[40] = {0,0,0,0,0,1,0,1,0,1,0,1,0,1,2,0,1,2,
                               0,1,2,0,1,2,0,1,2,3,0,1,2,3,
                               0,0,1,1,2,2,3,3};
  const int qt = qtab[item], ch = ctab[item];
  const int ns = (qt >> 1) + 1;             // causal s-tiles for this q-tile
  const int s0t = 2 * ch, s1t = min(2 * ch + 2, ns);
  const bool full = (ch == 0) && (qt <= 3);

  __shared__ u16 As[4096];    // Q-tile 64x64
  __shared__ u16 Bs[8192];    // K/ZT-tile 128x64
  __shared__ u16 Ps[8192];    // P 64x128, chunk-swizzle mod 16

  const int tid = threadIdx.x, w = tid >> 6, ln = tid & 63;
  const int g = ln >> 4, m = ln & 15;

  const u16* Qb = Qcat + (long)bh * 589824 + (long)qt * 64 * 576;
  const u16* Kb = Kcat + (long)b * 589824;
  const u16* Zb = ZT + (long)bh * 131072;

  f4_t O[8];
#pragma unroll
  for (int j = 0; j < 8; ++j) O[j] = (f4_t)0.f;
  float mrow[4], lrow[4];
#pragma unroll
  for (int r = 0; r < 4; ++r) { mrow[r] = -3e38f; lrow[r] = 0.f; }

  const float scale = 0.07216878364870322f;  // 1/sqrt(192)

  for (int st = s0t; st < s1t; ++st) {
    f4_t S[8];
#pragma unroll
    for (int j = 0; j < 8; ++j) S[j] = (f4_t)0.f;

    // ---- QK: 9 BK-iters over K=576
    for (int k0 = 0; k0 < 576; k0 += 64) {
#pragma unroll
      for (int q = 0; q < 2; ++q) {
        int r = 16 * w + 8 * q + (ln >> 3);
        int c = ((ln & 7) - r) & 7;
        glds16(&Qb[(long)r * 576 + k0 + c * 8], &As[(16 * w + 8 * q) * 64]);
      }
#pragma unroll
      for (int q = 0; q < 4; ++q) {
        int r = 32 * w + 8 * q + (ln >> 3);
        int c = ((ln & 7) - r) & 7;
        glds16(&Kb[(long)(st * 128 + r) * 576 + k0 + c * 8],
               &Bs[(32 * w + 8 * q) * 64]);
      }
      __syncthreads();
#pragma unroll
      for (int kh = 0; kh < 2; ++kh) {
        int qrow = 16 * w + m;
        bf8_t af = *(const bf8_t*)&As[qrow * 64 + (((kh * 4 + g) + qrow) & 7) * 8];
#pragma unroll
        for (int nt = 0; nt < 8; ++nt) {
          int row = nt * 16 + m;
          bf8_t bb = *(const bf8_t*)&Bs[row * 64 + (((kh * 4 + g) + row) & 7) * 8];
          S[nt] = __builtin_amdgcn_mfma_f32_16x16x32_bf16(af, bb, S[nt], 0, 0, 0);
        }
      }
      __syncthreads();
    }

    // ---- scale + causal mask (diag s-tile only)
    const bool diag = (st == (qt >> 1));
#pragma unroll
    for (int nt = 0; nt < 8; ++nt)
#pragma unroll
      for (int r = 0; r < 4; ++r) {
        float v = S[nt][r] * scale;
        if (diag &&
            (st * 128 + nt * 16 + m) > (qt * 64 + 16 * w + g * 4 + r))
          v = -3e38f;
        S[nt][r] = v;
      }

    // ---- online softmax (rows wave-local; 16-lane butterflies over m)
#pragma unroll
    for (int r = 0; r < 4; ++r) {
      float mx = S[0][r];
#pragma unroll
      for (int nt = 1; nt < 8; ++nt) mx = fmaxf(mx, S[nt][r]);
#pragma unroll
      for (int o = 1; o < 16; o <<= 1) mx = fmaxf(mx, __shfl_xor(mx, o, 64));
      float mn = fmaxf(mrow[r], mx);
      float al = __expf(mrow[r] - mn);
      mrow[r] = mn;
      float rs = 0.f;
#pragma unroll
      for (int nt = 0; nt < 8; ++nt) {
        float p = __expf(S[nt][r] - mn);
        S[nt][r] = p;
        rs += p;
      }
#pragma unroll
      for (int o = 1; o < 16; o <<= 1) rs += __shfl_xor(rs, o, 64);
      lrow[r] = lrow[r] * al + rs;
#pragma unroll
      for (int nt = 0; nt < 8; ++nt) O[nt][r] *= al;
    }

    // ---- P~ -> LDS (wave-local 16 rows; mod-16 chunk swizzle)
#pragma unroll
    for (int nt = 0; nt < 8; ++nt) {
      int colc = nt * 2 + (m >> 3), cole = m & 7;
#pragma unroll
      for (int r = 0; r < 4; ++r) {
        int row = 16 * w + g * 4 + r;
        Ps[row * 128 + ((colc + row) & 15) * 8 + cole] = f2bf(S[nt][r]);
      }
    }

    // ---- PV: O += P~ . ZT-sliceT (K=128, 2 BK-iters)
#pragma unroll
    for (int kb = 0; kb < 2; ++kb) {
      __syncthreads();  // Bs reuse guard
#pragma unroll
      for (int q = 0; q < 4; ++q) {
        int r = 32 * w + 8 * q + (ln >> 3);
        int c = ((ln & 7) - r) & 7;
        glds16(&Zb[(long)r * 1024 + st * 128 + kb * 64 + c * 8],
               &Bs[(32 * w + 8 * q) * 64]);
      }
      __syncthreads();
#pragma unroll
      for (int kh = 0; kh < 2; ++kh) {
        int qrow = 16 * w + m;
        int chk = kb * 8 + kh * 4 + g;
        bf8_t af = *(const bf8_t*)&Ps[qrow * 128 + ((chk + qrow) & 15) * 8];
#pragma unroll
        for (int nt = 0; nt < 8; ++nt) {
          int row = nt * 16 + m;
          bf8_t bb = *(const bf8_t*)&Bs[row * 64 + (((kh * 4 + g) + row) & 7) * 8];
          O[nt] = __builtin_amdgcn_mfma_f32_16x16x32_bf16(af, bb, O[nt], 0, 0, 0);
        }
      }
    }
    __syncthreads();  // protect As/Bs/Ps for next s-tile
  }

  if (full) {
    // ---- direct write: y = O/l (block saw the whole causal range)
    float* ob = out + ((long)b * Tv + qt * 64 + 16 * w) * 2048 + h * 128;
#pragma unroll
    for (int r = 0; r < 4; ++r) {
      float inv = 1.0f / lrow[r];
#pragma unroll
      for (int nt = 0; nt < 8; ++nt)
        ob[(long)(g * 4 + r) * 2048 + nt * 16 + m] = O[nt][r] * inv;
    }
  } else {
    // ---- emit partials: Opart (unnormalized), ml (m, l per row)
    float* Ob = Opart + (long)x * 8192;
#pragma unroll
    for (int r = 0; r < 4; ++r) {
      int row = 16 * w + g * 4 + r;
#pragma unroll
      for (int nt = 0; nt < 8; ++nt)
        Ob[(long)row * 128 + nt * 16 + m] = O[nt][r];
      if (m == 0) {
        ml[(long)x * 128 + row] = mrow[r];
        ml[(long)x * 128 + 64 + row] = lrow[r];
      }
    }
  }
}

// ---------------------------------------------------------------------------
// Split-flash pass 2: merge partials for qt>=4, write y fp32.
// Grid 1536 = (12 qt x 32 bh) x 4 row-groups; 256 thr = 8 rows x 32 float4.
// ---------------------------------------------------------------------------
__global__ __launch_bounds__(256) void attn_merge(
    const float* __restrict__ Opart, const float* __restrict__ ml,
    float* __restrict__ out) {
  const int i = blockIdx.x;
  const int rg = i & 3;                // 16-row group
  const int combo = i >> 2;            // 0..383
  const int bh = combo & 31, qt = 4 + (combo >> 5);  // 4..15
  const int b = bh >> 4, h = bh & 15;
  static const int NCH[16] = {1,1,1,1,2,2,2,2,3,3,3,3,4,4,4,4};
  static const int ITEM[64] = {
      32,0,0,0,  33,0,0,0,  0,0,0,0,   1,0,0,0,
      2,34,0,0,  3,35,0,0,  4,5,0,0,   6,7,0,0,
      8,9,36,0,  10,11,37,0, 12,13,14,0, 15,16,17,0,
      18,19,20,38, 21,22,23,39, 24,25,26,27, 28,29,30,31};
  const int nch = NCH[qt];
  const int r = threadIdx.x >> 5, c4 = threadIdx.x & 31;
  float* ob = out + ((long)b * Tv + qt * 64 + rg * 16) * 2048 + h * 128;
#pragma unroll
  for (int rr = 0; rr < 2; ++rr) {
    const int lrow = r + rr * 8;          // 0..15 within group
    const int row = rg * 16 + lrow;       // 0..63 absolute
    float M = -3e38f, mi[4], li[4];
    for (int k = 0; k < nch; ++k) {
      long p = (long)ITEM[qt * 4 + k] * 32 + bh;
      mi[k] = ml[p * 128 + row];
      li[k] = ml[p * 128 + 64 + row];
      M = fmaxf(M, mi[k]);
    }
    float L = 0.f;
    float ax = 0.f, ay = 0.f, az = 0.f, aw = 0.f;
    for (int k = 0; k < nch; ++k) {
      long p = (long)ITEM[qt * 4 + k] * 32 + bh;
      float e = __expf(mi[k] - M);
      L += li[k] * e;
      float4 v = *(const float4*)&Opart[p * 8192 + (long)row * 128 + c4 * 4];
      ax += v.x * e; ay += v.y * e; az += v.z * e; aw += v.w * e;
    }
    const float inv = 1.0f / L;
    float4 o4 = {ax * inv, ay * inv, az * inv, aw * inv};
    *(float4*)&ob[(long)lrow * 2048 + c4 * 4] = o4;
  }
}

// ---------------------------------------------------------------------------
// prep_all: fused (a) fp32->bf16 casts (5 segments) + Wkr pad into W3
// [blocks 0..11135] and (b) 3 transpose-cast jobs [blocks 11136..14207]:
// job0 Wuk(2048x512)->WukT, job1 Wuv->WuvT, job2 Wuq viewed(512x2048)->WuqT.
// ---------------------------------------------------------------------------
struct PrepArgs {
  const float* src[5];
  u16* dst[5];
  long cum[6];
  const float* wkr;
  u16* w3;
  const float* ts[3];
  u16* td[3];
};
__global__ __launch_bounds__(256) void prep_all(PrepArgs a) {
  __shared__ u16 sm[32][33];
  const int bid = blockIdx.x;
  if (bid < 11136) {
    long i = (long)bid * 256 + threadIdx.x;
    if (i < 2752512) {
      int seg = 0;
      while (i >= a.cum[seg + 1]) ++seg;
      long j = i - a.cum[seg];
      float4 vv = ((const float4*)a.src[seg])[j];
      u16x4 o;
      o[0] = f2bf(vv.x); o[1] = f2bf(vv.y); o[2] = f2bf(vv.z); o[3] = f2bf(vv.w);
      ((u16x4*)a.dst[seg])[j] = o;
    } else {
      long j = i - 2752512;  // < 98304
      u16x4* W4 = (u16x4*)a.w3;
      if (j < 32768) {
        float4 vv = ((const float4*)a.wkr)[j];
        u16x4 o;
        o[0] = f2bf(vv.x); o[1] = f2bf(vv.y); o[2] = f2bf(vv.z); o[3] = f2bf(vv.w);
        W4[557056 + j] = o;                    // rows 1088..1151
      } else if (j < 65536) {
        W4[262144 + (j - 32768)] = (u16x4)0;   // rows 512..575
      } else {
        W4[589824 + (j - 65536)] = (u16x4)0;   // rows 1152..1215
      }
    }
  } else {
    const int t = bid - 11136;           // 0..3071
    const int job = t >> 10, tt = t & 1023;
    const float* in = a.ts[job];
    u16* out = a.td[job];
    const int R = (job == 2) ? 512 : 2048;
    const int C = (job == 2) ? 2048 : 512;
    const int xt = (job == 2) ? 64 : 16;   // C/32 tiles along columns
    const int x = tt % xt, y = tt / xt;
    const int c0 = x * 32, r0 = y * 32;
    const int tx = threadIdx.x & 31, ty = threadIdx.x >> 5;
    for (int i = ty; i < 32; i += 8)
      sm[i][tx] = f2bf(in[(long)(r0 + i) * C + c0 + tx]);
    __syncthreads();
    for (int i = ty; i < 32; i += 8)
      out[(long)(c0 + i) * R + r0 + tx] = sm[tx][i];
  }
}

// ---------------------------------------------------------------------------
// merge3_rope: fused (a) q_abs GEMM [blocks 0..1023, XCD-swizzled]: per head
// h, Qcat[b,h,:,0:512] = qup[b,:,h*128:(h+1)*128] @ WukT_h^T (K=128, 128x128
// tiles, single-buffered, bf16 out) and (b) ropes [blocks 1024..5375]:
// Kcat cols 512.. in place + rope+scatter cqr -> Qcat cols 512...
// Outputs disjoint (GEMM: Qcat cols 0..511; rope: cols 512..575 / Kcat).
// ---------------------------------------------------------------------------
__global__ __launch_bounds__(256) void merge3_rope(
    const u16* __restrict__ qup, const u16* __restrict__ WukT,
    u16* __restrict__ Qcat, u16* __restrict__ Kcat,
    const u16* __restrict__ cqr,
    const float* __restrict__ cosf, const float* __restrict__ sinf) {
  __shared__ u16 SMEM[16384];
  const int bid0 = blockIdx.x;
  if (bid0 < 1024) {
    // T1: XCD-aware bijective remap within the 1024 GEMM blocks
    const int bid = (bid0 & 7) * 128 + (bid0 >> 3);
    // ---- q_abs GEMM: ntx=4, nty=8, z = b*16 + h
    const int x = bid & 3;
    int rest = bid >> 2;
    const int y = rest & 7;
    const int z = rest >> 3;             // 0..31
    const int z1 = z >> 4, z2 = z & 15;  // batch, head
    const u16* A = qup + (long)z1 * 2097152 + z2 * 128;
    const u16* B = WukT + z2 * 128;
    u16* C = Qcat + (long)z1 * 9437184 + (long)z2 * 589824;
    const int m0 = y * 128, n0 = x * 128;
    u16* As = SMEM;
    u16* Bs = SMEM + 8192;

    const int tid = threadIdx.x, w = tid >> 6, ln = tid & 63;
    const int my = w >> 1, mx = w & 1;
    const int g = ln >> 4, m = ln & 15;

    f4_t acc[4][4];
#pragma unroll
    for (int i = 0; i < 4; ++i)
#pragma unroll
      for (int j = 0; j < 4; ++j) acc[i][j] = (f4_t)0.f;

    for (int k0 = 0; k0 < 128; k0 += 64) {
#pragma unroll
      for (int q = 0; q < 4; ++q) {
        int r = 32 * w + 8 * q + (ln >> 3);
        int c = ((ln & 7) - r) & 7;
        glds16(&A[(long)(m0 + r) * 2048 + k0 + c * 8],
               &As[(32 * w + 8 * q) * 64]);
        glds16(&B[(long)(n0 + r) * 2048 + k0 + c * 8],
               &Bs[(32 * w + 8 * q) * 64]);
      }
      __syncthreads();
#pragma unroll
      for (int kh = 0; kh < 2; ++kh) {
        bf8_t af[4], bg[4];
#pragma unroll
        for (int mt = 0; mt < 4; ++mt) {
          int row = my * 64 + mt * 16 + m;
          af[mt] = *(const bf8_t*)&As[row * 64 + (((kh * 4 + g) + row) & 7) * 8];
        }
#pragma unroll
        for (int nt = 0; nt < 4; ++nt) {
          int row = mx * 64 + nt * 16 + m;
          bg[nt] = *(const bf8_t*)&Bs[row * 64 + (((kh * 4 + g) + row) & 7) * 8];
        }
#pragma unroll
        for (int mt = 0; mt < 4; ++mt)
#pragma unroll
          for (int nt = 0; nt < 4; ++nt)
            acc[mt][nt] = __builtin_amdgcn_mfma_f32_16x16x32_bf16(
                af[mt], bg[nt], acc[mt][nt], 0, 0, 0);
      }
      __syncthreads();
    }

    u16* Es = SMEM + w * 4096;
#pragma unroll
    for (int mt = 0; mt < 4; ++mt)
#pragma unroll
      for (int nt = 0; nt < 4; ++nt)
#pragma unroll
        for (int r = 0; r < 4; ++r) {
          int row = mt * 16 + g * 4 + r;
          int col = nt * 16 + m;
          Es[row * 64 + (((col >> 3) + row) & 7) * 8 + (col & 7)] =
              f2bf(acc[mt][nt][r]);
        }
    __syncthreads();
    const long rowbase = (long)(m0 + my * 64 + ln) * 576 + n0 + mx * 64;
#pragma unroll
    for (int c = 0; c < 8; ++c) {
      u16x8 v = *(const u16x8*)&Es[ln * 64 + ((c + ln) & 7) * 8];
      *(u16x8*)&C[rowbase + c * 8] = v;
    }
  } else {
    // ---- ropes
    int idx = (bid0 - 1024) * 256 + threadIdx.x;  // < 1,114,112
    if (idx < 65536) {
      int i = idx & 31, t = (idx >> 5) & 1023, b = idx >> 15;
      float c = cosf[t * 32 + i], s = sinf[t * 32 + i];
      u16* p = Kcat + ((long)(b * Tv + t) * 576 + 512 + 2 * i);
      float re = bf2f(p[0]), im = bf2f(p[1]);
      p[0] = f2bf(re * c - im * s);
      p[1] = f2bf(re * s + im * c);
    } else {
      int j = idx - 65536;  // < 1,048,576
      int i = j & 31, h = (j >> 5) & 15, t = (j >> 9) & 1023, b = j >> 19;
      float c = cosf[t * 32 + i], s = sinf[t * 32 + i];
      const u16* src = cqr + ((long)(b * Tv + t) * 1024 + h * 64 + 2 * i);
      float re = bf2f(src[0]), im = bf2f(src[1]);
      u16* dst = Qcat + (((long)(b * NHv + h) * Tv + t) * 576 + 512 + 2 * i);
      dst[0] = f2bf(re * c - im * s);
      dst[1] = f2bf(re * s + im * c);
    }
  }
}

// Reduce 4 fp32 split-K partials (2048x512) -> bf16 veffT
__global__ void vred(const float* __restrict__ P, u16* __restrict__ veffT) {
  int i = blockIdx.x * 256 + threadIdx.x;  // < 262144
  float4 v0 = ((const float4*)P)[i];
  float4 v1 = ((const float4*)P)[262144 + i];
  float4 v2 = ((const float4*)P)[524288 + i];
  float4 v3 = ((const float4*)P)[786432 + i];
  u16x4 o;
  o[0] = f2bf(v0.x + v1.x + v2.x + v3.x);
  o[1] = f2bf(v0.y + v1.y + v2.y + v3.y);
  o[2] = f2bf(v0.z + v1.z + v2.z + v3.z);
  o[3] = f2bf(v0.w + v1.w + v2.w + v3.w);
  ((u16x4*)veffT)[i] = o;
}

// ---------------------------------------------------------------------------
// kernel_launch
// ---------------------------------------------------------------------------
extern "C" void kernel_launch(void* const* d_in, const int* in_sizes, int n_in,
                              void* d_out, int out_size, void* d_ws,
                              size_t ws_size, hipStream_t stream) {
  const float* x    = (const float*)d_in[0];
  const float* fcos = (const float*)d_in[1];
  const float* fsin = (const float*)d_in[2];
  const float* Wdq  = (const float*)d_in[3];
  const float* Wuq  = (const float*)d_in[4];
  const float* Wdkv = (const float*)d_in[5];
  const float* Wuk  = (const float*)d_in[6];
  const float* Wuv  = (const float*)d_in[7];
  const float* Wqr  = (const float*)d_in[8];
  const float* Wkr  = (const float*)d_in[9];
  const float* Wo   = (const float*)d_in[10];
  float* out = (float*)d_out;

  // ---- workspace carve-up (u16 units; total ~154 MB < 256 MiB)
  u16* ws = (u16*)d_ws;
  u16* cq     = ws;                  // (2048x576)        1,179,648
  u16* Kcat   = cq + 1179648;        // (B,T,576)         1,179,648
  u16* veffT  = Kcat + 1179648;      // (2048x512)        1,048,576
  u16* Qcat   = veffT + 1048576;     // (B,NH,T,576)     18,874,368
  u16* W3     = Qcat + 18874368;     // (1216x2048)       2,490,368
  u16* x_bf   = W3 + 2490368;        //                   4,194,304
  u16* Wqr_bf = x_bf + 4194304;      //                     524,288
  u16* WuqT   = Wqr_bf + 524288;     // (2048x512) = U^T  1,048,576
  u16* Wo_bf  = WuqT + 1048576;      //                   4,194,304
  u16* WukT   = Wo_bf + 4194304;     // (512x2048)        1,048,576
  u16* WuvT   = WukT + 1048576;      // (512x2048)        1,048,576
  u16* cqr    = WuvT + 1048576;      // (B,T,1024)        2,097,152
  u16* qup    = cqr + 2097152;       // (2048x2048)       4,194,304
  u16* ZTbuf  = qup + 4194304;       // (B,NH,128,1024)   4,194,304
  float* Vprt  = (float*)(ZTbuf + 4194304);   // 4x(2048x512) fp32
  float* Opart = Vprt + 4194304;              // 1280x64x128 fp32
  float* mlbuf = Opart + 10485760;            // 1280x2x64 fp32

  // ---- 1) prep: casts (+Wkr pad) + 3 transpose-casts, one launch
  {
    PrepArgs a;
    a.src[0] = x;    a.dst[0] = x_bf;
    a.src[1] = Wdq;  a.dst[1] = W3;
    a.src[2] = Wdkv; a.dst[2] = W3 + 576 * 2048;
    a.src[3] = Wqr;  a.dst[3] = Wqr_bf;
    a.src[4] = Wo;   a.dst[4] = Wo_bf;
    a.cum[0] = 0;        a.cum[1] = 1048576; a.cum[2] = 1310720;
    a.cum[3] = 1572864;  a.cum[4] = 1703936; a.cum[5] = 2752512;
    a.wkr = Wkr; a.w3 = W3;
    a.ts[0] = Wuk; a.td[0] = WukT;
    a.ts[1] = Wuv; a.td[1] = WuvT;
    a.ts[2] = Wuq; a.td[2] = WuqT;   // Wuq viewed (512x2048) -> U^T
    prep_all<<<14208, 256, 0, stream>>>(a);
  }

  // ---- 2) merge1: QKV(160) + veffT split-K(256) = 416 blocks (dbuf GEMM)
  {
    JobPack3 P;
    P.j[0] = {x_bf, W3, cq, 0, 0, (long)576 * 2048, 0, 1179648, 0,
              2048, 2048, 2048, 576, 576, 1, 5, 16, 1};
    P.j[1] = {Wo_bf, WuvT, Vprt, 512, 0, 512, 0, 1048576, 0,
              512, 2048, 2048, 512, 512, 1, 4, 16, 0};
    P.j[2] = P.j[1];  // unused
    P.cum[0] = 0; P.cum[1] = 160; P.cum[2] = 416; P.cum[3] = 416;
    gemm_db<<<416, 256, 0, stream>>>(P);
  }
  vred<<<1024, 256, 0, stream>>>(Vprt, veffT);

  // ---- 3) merge2: q_up(256) + ZT(256) + c_qr(128) = 640 blocks (dbuf GEMM)
  {
    JobPack3 P;
    P.j[0] = {cq, WuqT, qup, 0, 0, 0, 0, 0, 0,
              512, 576, 512, 2048, 2048, 1, 16, 16, 1};
    P.j[1] = {veffT, Kcat, ZTbuf, 0, 65536, 589824, 0, 2097152, 131072,
              512, 512, 576, 1024, 1024, 16, 8, 1, 1};
    P.j[2] = {cq, Wqr_bf, cqr, 0, 0, 0, 0, 0, 0,
              512, 576, 512, 1024, 1024, 1, 8, 16, 1};
    P.cum[0] = 0; P.cum[1] = 256; P.cum[2] = 512; P.cum[3] = 640;
    gemm_db<<<640, 256, 0, stream>>>(P);
  }

  // ---- 4) merge3 (q_abs, 1024 blocks) + ropes (4352 blocks), one launch
  merge3_rope<<<5376, 256, 0, stream>>>(qup, WukT, Qcat, Kcat, cqr,
                                        fcos, fsin);

  // ---- 5) split-flash attention
  attn_part<<<1280, 256, 0, stream>>>(Qcat, Kcat, ZTbuf, Opart, mlbuf, out);
  attn_merge<<<1536, 256, 0, stream>>>(Opart, mlbuf, out);
}